// Round 15
// baseline (389.632 us; speedup 1.0000x reference)
//
#include <hip/hip_runtime.h>
#include <math.h>

#define NB 1024
#define NC 63
#define NF 250
#define NH 4
#define ND 250
#define NHD 1000

typedef __bf16 bf16x8 __attribute__((ext_vector_type(8)));
typedef float f32x4 __attribute__((ext_vector_type(4)));

// ============================================================================
// k_fused (R12 version, reverted): one batch per block, 64KB LDS.
// ============================================================================
__global__ __launch_bounds__(256) void k_fused(const float* __restrict__ x,
                                               const __bf16* __restrict__ WcT,
                                               const float* __restrict__ biasc,
                                               float* __restrict__ out,
                                               float* __restrict__ partial) {
    __shared__ __align__(16) __bf16 Xh[64 * 256];   // 32 KB (rows 0-1 overlay moments post-compute)
    __shared__ __align__(16) __bf16 Xl[64 * 256];   // 32 KB
    float* const momS = (float*)Xh;  // [0:64)=S [64:128)=SS [128:192)=mean [192:256)=scl
    const int t = threadIdx.x;
    const int w = t >> 6, l = t & 63;
    const int l16 = l & 15, lq = l >> 4;
    const int swz = (l16 & 7) << 3;
    const int nb = w * 64;

    {
        const int kz = t ^ 56;                 // (63&7)<<3
        Xh[63 * 256 + kz] = (__bf16)1.0f;
        Xl[63 * 256 + kz] = (__bf16)0.0f;
    }

    float bc[4];
#pragma unroll
    for (int ni = 0; ni < 4; ++ni) {
        const int col = nb + ni * 16 + l16;
        bc[ni] = (col < ND) ? biasc[col] : 0.f;
    }

    const f32x4 z4 = {0.f, 0.f, 0.f, 0.f};
    const int b = blockIdx.x;
    const float* xb = x + (size_t)b * (NC * NF);

    // ---- stage: 63 rows x 32 octets, coalesced float2 -> hi/lo bf16
#pragma unroll
    for (int it = 0; it < 8; ++it) {
        const int u = it * 256 + t;
        if (u < 2016) {
            const int row = u >> 5;
            const int ko = (u & 31) << 3;
            const float* src = xb + row * NF + ko;
            float v[8];
#pragma unroll
            for (int q = 0; q < 4; ++q) {
                if (ko + q * 2 < NF) {
                    const float2 p = *(const float2*)(src + q * 2);
                    v[2 * q] = p.x; v[2 * q + 1] = p.y;
                } else { v[2 * q] = 0.f; v[2 * q + 1] = 0.f; }
            }
            bf16x8 h, lo_;
#pragma unroll
            for (int j = 0; j < 8; ++j) {
                h[j] = (__bf16)v[j];
                lo_[j] = (__bf16)(v[j] - (float)h[j]);
            }
            const int kS = ko ^ ((row & 7) << 3);
            *(bf16x8*)&Xh[row * 256 + kS] = h;
            *(bf16x8*)&Xl[row * 256 + kS] = lo_;
        }
    }
    __syncthreads();   // staging complete

    bf16x8 bfr[4][4];
    f32x4 accM[4][4];
    f32x4 accG[4];
#pragma unroll
    for (int mi = 0; mi < 4; ++mi)
#pragma unroll
        for (int ni = 0; ni < 4; ++ni) accM[mi][ni] = z4;
#pragma unroll
    for (int ni = 0; ni < 4; ++ni) accG[ni] = z4;

    const int garow = (16 * w + l16) * 256;   // gram A row base

    // ================= K half 0 (kc 0..3) =================
#pragma unroll
    for (int ni = 0; ni < 4; ++ni) {
        const int n = nb + ni * 16 + l16;
#pragma unroll
        for (int kk = 0; kk < 4; ++kk)
            bfr[ni][kk] = *(const bf16x8*)(WcT + (size_t)n * 256 + kk * 32 + lq * 8);
    }
#pragma unroll
    for (int kk = 0; kk < 4; ++kk) {
        const int kb = (kk * 32 + lq * 8) ^ swz;
        bf16x8 hi[4], lo[4];
#pragma unroll
        for (int r = 0; r < 4; ++r) {
            hi[r] = *(const bf16x8*)&Xh[(r * 16 + l16) * 256 + kb];
            lo[r] = *(const bf16x8*)&Xl[(r * 16 + l16) * 256 + kb];
        }
        const bf16x8 ah = *(const bf16x8*)&Xh[garow + kb];
        const bf16x8 al = *(const bf16x8*)&Xl[garow + kb];
#pragma unroll
        for (int mi = 0; mi < 4; ++mi)
#pragma unroll
            for (int ni = 0; ni < 4; ++ni)
                accM[mi][ni] = __builtin_amdgcn_mfma_f32_16x16x32_bf16(
                    hi[mi], bfr[ni][kk], accM[mi][ni], 0, 0, 0);
#pragma unroll
        for (int ni = 0; ni < 4; ++ni) {
            accG[ni] = __builtin_amdgcn_mfma_f32_16x16x32_bf16(ah, hi[ni], accG[ni], 0, 0, 0);
            accG[ni] = __builtin_amdgcn_mfma_f32_16x16x32_bf16(ah, lo[ni], accG[ni], 0, 0, 0);
            accG[ni] = __builtin_amdgcn_mfma_f32_16x16x32_bf16(al, hi[ni], accG[ni], 0, 0, 0);
        }
    }

    // ================= K half 1 (kc 4..7) =================
#pragma unroll
    for (int ni = 0; ni < 4; ++ni) {
        const int n = nb + ni * 16 + l16;
#pragma unroll
        for (int kk = 0; kk < 4; ++kk)
            bfr[ni][kk] = *(const bf16x8*)(WcT + (size_t)n * 256 + (4 + kk) * 32 + lq * 8);
    }
#pragma unroll
    for (int kk = 0; kk < 4; ++kk) {
        const int kb = ((4 + kk) * 32 + lq * 8) ^ swz;
        bf16x8 hi[4], lo[4];
#pragma unroll
        for (int r = 0; r < 4; ++r) {
            hi[r] = *(const bf16x8*)&Xh[(r * 16 + l16) * 256 + kb];
            lo[r] = *(const bf16x8*)&Xl[(r * 16 + l16) * 256 + kb];
        }
        const bf16x8 ah = *(const bf16x8*)&Xh[garow + kb];
        const bf16x8 al = *(const bf16x8*)&Xl[garow + kb];
#pragma unroll
        for (int mi = 0; mi < 4; ++mi)
#pragma unroll
            for (int ni = 0; ni < 4; ++ni)
                accM[mi][ni] = __builtin_amdgcn_mfma_f32_16x16x32_bf16(
                    hi[mi], bfr[ni][kk], accM[mi][ni], 0, 0, 0);
#pragma unroll
        for (int ni = 0; ni < 4; ++ni) {
            accG[ni] = __builtin_amdgcn_mfma_f32_16x16x32_bf16(ah, hi[ni], accG[ni], 0, 0, 0);
            accG[ni] = __builtin_amdgcn_mfma_f32_16x16x32_bf16(ah, lo[ni], accG[ni], 0, 0, 0);
            accG[ni] = __builtin_amdgcn_mfma_f32_16x16x32_bf16(al, hi[ni], accG[ni], 0, 0, 0);
        }
    }

    __syncthreads();   // ALL plane reads done before overlay write (alias hazard)

    if (l16 == 15) {
#pragma unroll
        for (int r = 0; r < 4; ++r) momS[16 * w + lq * 4 + r] = accG[3][r];
    }
    if ((l16 >> 2) == lq) momS[64 + 16 * w + l16] = accG[w][l16 & 3];
    __syncthreads();
    if (t < 64) {
        const float S = momS[t], SSv = momS[64 + t];
        float m = S * (1.f / (float)NF);
        const float var = (SSv - S * S * (1.f / (float)NF)) * (1.f / (float)(NF - 1));
        float sc = 1.f / (sqrtf(var) + 1e-8f);
        if (t >= NC) { m = 0.f; sc = 0.f; }
        momS[128 + t] = m; momS[192 + t] = sc;
    }
    __syncthreads();

    float mr[4], sr[4];
#pragma unroll
    for (int r = 0; r < 4; ++r) {
        const int row = 16 * w + lq * 4 + r;
        mr[r] = momS[128 + row]; sr[r] = momS[192 + row];
    }
#pragma unroll
    for (int ni = 0; ni < 4; ++ni) {
        const float mc = momS[128 + 16 * ni + l16];
        const float sc = momS[192 + 16 * ni + l16];
#pragma unroll
        for (int r = 0; r < 4; ++r) {
            const int row = 16 * w + lq * 4 + r;
            const int col = 16 * ni + l16;
            partial[(size_t)b * 4096 + row * 64 + col] =
                (accG[ni][r] - (float)NF * mr[r] * mc) * sr[r] * sc;
        }
    }

    const size_t ob = (size_t)b * NC;
#pragma unroll
    for (int mi = 0; mi < 4; ++mi) {
#pragma unroll
        for (int r = 0; r < 4; ++r) {
            const int rt = mi * 16 + lq * 4 + r;
            if (rt < NC) {
#pragma unroll
                for (int ni = 0; ni < 4; ++ni) {
                    const int col = nb + ni * 16 + l16;
                    if (col < ND)
                        out[(ob + rt) * ND + col] = accM[mi][ni][r] + bc[ni];
                }
            }
        }
    }
}

// ============================================================================
// DIAGNOSTIC ablation kernels (outputs unaffected; checksums -> ws scratch).
// MODE 1: 8x (stage + barrier + LDS checksum)  -> dur/8 = stage phase S.
// MODE 2: 1x stage + 8x (B-load + 224 MFMA)    -> (dur - S)/8 = compute C.
// ============================================================================
template<int MODE>
__global__ __launch_bounds__(256) void k_abl(const float* __restrict__ x,
                                             const __bf16* __restrict__ WcT,
                                             float* __restrict__ abl) {
    __shared__ __align__(16) __bf16 Xh[64 * 256];
    __shared__ __align__(16) __bf16 Xl[64 * 256];
    const int t = threadIdx.x;
    const int w = t >> 6, l = t & 63;
    const int l16 = l & 15, lq = l >> 4;
    const int swz = (l16 & 7) << 3;
    const int nb = w * 64;
    const int b = blockIdx.x;
    const float* xb = x + (size_t)b * (NC * NF);
    {
        const int kz = t ^ 56;
        Xh[63 * 256 + kz] = (__bf16)1.0f;
        Xl[63 * 256 + kz] = (__bf16)0.0f;
    }
    float cks = 0.f;

    if constexpr (MODE == 1) {
        for (int rep = 0; rep < 8; ++rep) {
            __syncthreads();
#pragma unroll
            for (int it = 0; it < 8; ++it) {
                const int u = it * 256 + t;
                if (u < 2016) {
                    const int row = u >> 5;
                    const int ko = (u & 31) << 3;
                    const float* src = xb + row * NF + ko;
                    float v[8];
#pragma unroll
                    for (int q = 0; q < 4; ++q) {
                        if (ko + q * 2 < NF) {
                            const float2 p = *(const float2*)(src + q * 2);
                            v[2 * q] = p.x; v[2 * q + 1] = p.y;
                        } else { v[2 * q] = 0.f; v[2 * q + 1] = 0.f; }
                    }
                    bf16x8 h, lo_;
#pragma unroll
                    for (int j = 0; j < 8; ++j) {
                        h[j] = (__bf16)v[j];
                        lo_[j] = (__bf16)(v[j] - (float)h[j]);
                    }
                    const int kS = ko ^ ((row & 7) << 3);
                    *(bf16x8*)&Xh[row * 256 + kS] = h;
                    *(bf16x8*)&Xl[row * 256 + kS] = lo_;
                }
            }
            __syncthreads();
            cks += (float)Xh[(t * 37 + rep * 101) & 16383]
                 + (float)Xl[(t * 53 + rep * 29) & 16383];
        }
    } else {
        // ---- stage once (identical to k_fused)
#pragma unroll
        for (int it = 0; it < 8; ++it) {
            const int u = it * 256 + t;
            if (u < 2016) {
                const int row = u >> 5;
                const int ko = (u & 31) << 3;
                const float* src = xb + row * NF + ko;
                float v[8];
#pragma unroll
                for (int q = 0; q < 4; ++q) {
                    if (ko + q * 2 < NF) {
                        const float2 p = *(const float2*)(src + q * 2);
                        v[2 * q] = p.x; v[2 * q + 1] = p.y;
                    } else { v[2 * q] = 0.f; v[2 * q + 1] = 0.f; }
                }
                bf16x8 h, lo_;
#pragma unroll
                for (int j = 0; j < 8; ++j) {
                    h[j] = (__bf16)v[j];
                    lo_[j] = (__bf16)(v[j] - (float)h[j]);
                }
                const int kS = ko ^ ((row & 7) << 3);
                *(bf16x8*)&Xh[row * 256 + kS] = h;
                *(bf16x8*)&Xl[row * 256 + kS] = lo_;
            }
        }
        __syncthreads();

        const f32x4 z4 = {0.f, 0.f, 0.f, 0.f};
        bf16x8 bfr[4][4];
        f32x4 accM[4][4];
        f32x4 accG[4];
#pragma unroll
        for (int mi = 0; mi < 4; ++mi)
#pragma unroll
            for (int ni = 0; ni < 4; ++ni) accM[mi][ni] = z4;
#pragma unroll
        for (int ni = 0; ni < 4; ++ni) accG[ni] = z4;
        const int garow = (16 * w + l16) * 256;

        for (int rep = 0; rep < 8; ++rep) {
#pragma unroll
            for (int half = 0; half < 2; ++half) {
#pragma unroll
                for (int ni = 0; ni < 4; ++ni) {
                    const int n = nb + ni * 16 + l16;
#pragma unroll
                    for (int kk = 0; kk < 4; ++kk)
                        bfr[ni][kk] = *(const bf16x8*)(WcT + (size_t)n * 256 +
                                                       (half * 4 + kk) * 32 + lq * 8);
                }
#pragma unroll
                for (int kk = 0; kk < 4; ++kk) {
                    const int kb = ((half * 4 + kk) * 32 + lq * 8) ^ swz;
                    bf16x8 hi[4], lo[4];
#pragma unroll
                    for (int r = 0; r < 4; ++r) {
                        hi[r] = *(const bf16x8*)&Xh[(r * 16 + l16) * 256 + kb];
                        lo[r] = *(const bf16x8*)&Xl[(r * 16 + l16) * 256 + kb];
                    }
                    const bf16x8 ah = *(const bf16x8*)&Xh[garow + kb];
                    const bf16x8 al = *(const bf16x8*)&Xl[garow + kb];
#pragma unroll
                    for (int mi = 0; mi < 4; ++mi)
#pragma unroll
                        for (int ni = 0; ni < 4; ++ni)
                            accM[mi][ni] = __builtin_amdgcn_mfma_f32_16x16x32_bf16(
                                hi[mi], bfr[ni][kk], accM[mi][ni], 0, 0, 0);
#pragma unroll
                    for (int ni = 0; ni < 4; ++ni) {
                        accG[ni] = __builtin_amdgcn_mfma_f32_16x16x32_bf16(ah, hi[ni], accG[ni], 0, 0, 0);
                        accG[ni] = __builtin_amdgcn_mfma_f32_16x16x32_bf16(ah, lo[ni], accG[ni], 0, 0, 0);
                        accG[ni] = __builtin_amdgcn_mfma_f32_16x16x32_bf16(al, hi[ni], accG[ni], 0, 0, 0);
                    }
                }
            }
        }
#pragma unroll
        for (int mi = 0; mi < 4; ++mi)
#pragma unroll
            for (int ni = 0; ni < 4; ++ni)
#pragma unroll
                for (int r = 0; r < 4; ++r) cks += accM[mi][ni][r];
#pragma unroll
        for (int ni = 0; ni < 4; ++ni)
#pragma unroll
            for (int r = 0; r < 4; ++r) cks += accG[ni][r];
    }
    abl[(size_t)b * 256 + t] = cks;
}

// ============================================================================
// Reduce 1024 partials -> adj (63x63). grid 63 rows x 512 thr. (unchanged)
// ============================================================================
__global__ __launch_bounds__(512) void k_adj_reduce(const float* __restrict__ partial,
                                                    float* __restrict__ adj) {
    __shared__ float red[8][64];
    const int row = blockIdx.x, t = threadIdx.x;
    const int c = t & 63, g = t >> 6;
    float s = 0.f;
    const float* p = partial + (size_t)(g * 128) * 4096 + row * 64 + c;
#pragma unroll 8
    for (int i = 0; i < 128; ++i) s += p[(size_t)i * 4096];
    red[g][c] = s;
    __syncthreads();
    if (t < NC) {
        float tot = 0.f;
#pragma unroll
        for (int gg = 0; gg < 8; ++gg) tot += red[gg][t];
        adj[row * NC + t] = tot * (1.f / ((float)NF * (float)NB));
    }
}

// ============================================================================
// k_gs (unchanged)
// ============================================================================
__global__ __launch_bounds__(256) void k_gs(const float* __restrict__ Wg,
                                            const float* __restrict__ att_src,
                                            const float* __restrict__ att_dst,
                                            float* __restrict__ gs,
                                            float* __restrict__ gd) {
    const int f = blockIdx.x;
    const int h = threadIdx.x >> 6, l = threadIdx.x & 63;
    const float* wr = Wg + (size_t)f * NHD + h * ND;
    const float* sp = att_src + h * ND;
    const float* dp = att_dst + h * ND;
    float s = 0.f, d = 0.f;
#pragma unroll
    for (int q = 0; q < 4; ++q) {
        const int dd = l + q * 64;
        if (dd < ND) {
            const float wv = wr[dd];
            s += wv * sp[dd];
            d += wv * dp[dd];
        }
    }
#pragma unroll
    for (int off = 32; off >= 1; off >>= 1) {
        s += __shfl_down(s, off);
        d += __shfl_down(d, off);
    }
    if (l == 0) { gs[f * NH + h] = s; gd[f * NH + h] = d; }
}

// ============================================================================
// k_asad (unchanged)
// ============================================================================
__global__ __launch_bounds__(512) void k_asad(const float* __restrict__ x,
                                              const float* __restrict__ gs,
                                              const float* __restrict__ gd,
                                              float* __restrict__ as_,
                                              float* __restrict__ ad_) {
    __shared__ float x0S[NC * NF];
    __shared__ float gsS[NF * NH], gdS[NF * NH];
    const int t = threadIdx.x;
    for (int e = t; e < NC * NF; e += 512) x0S[e] = x[e];
    for (int e = t; e < NF * NH; e += 512) { gsS[e] = gs[e]; gdS[e] = gd[e]; }
    __syncthreads();
    if (t < NC * NH) {
        const int c = t >> 2, h = t & 3;
        float s = 0.f, d = 0.f;
#pragma unroll 5
        for (int f = 0; f < NF; ++f) {
            const float xv = x0S[c * NF + f];
            s += xv * gsS[f * NH + h];
            d += xv * gdS[f * NH + h];
        }
        as_[t] = s; ad_[t] = d;
    }
}

// ============================================================================
// k_out0 (unchanged)
// ============================================================================
__global__ __launch_bounds__(512) void k_out0(const float* __restrict__ adj,
                                              const float* __restrict__ as_,
                                              const float* __restrict__ ad_,
                                              const float* __restrict__ hp,
                                              const float* __restrict__ biasc,
                                              float* __restrict__ out) {
    __shared__ float adjS[NC * NC];
    __shared__ float thS[NC];
    __shared__ float asS[NC * 5];
    __shared__ float adS[NC * NH];
    __shared__ float wS[256];
    __shared__ float psum[2][256];
    const int j = blockIdx.x, t = threadIdx.x;
    const int w = t >> 6, l = t & 63;

    for (int e = t; e < NC * NC; e += 512) adjS[e] = adj[e];
    if (t < NC * NH) { asS[(t >> 2) * 5 + (t & 3)] = as_[t]; adS[t] = ad_[t]; }
    __syncthreads();

    for (int r = w; r < NC; r += 8) {
        const float v = (l < NC) ? adjS[r * NC + l] : -INFINITY;
        float prev = INFINITY;
        int krem = 8;
        float th = -INFINITY;
#pragma unroll
        for (int iter = 0; iter < 8; ++iter) {
            const float vm = (v < prev) ? v : -INFINITY;
            float m = vm;
#pragma unroll
            for (int off = 32; off >= 1; off >>= 1) m = fmaxf(m, __shfl_xor(m, off));
            const unsigned long long bl = __ballot(vm == m);
            const int cnt = __popcll(bl);
            if (cnt >= krem) { th = m; break; }
            krem -= cnt; prev = m;
        }
        if (l == 0) thS[r] = th;
    }
    __syncthreads();

    if (w < NH) {
        const int h = w, i = l;
        const float adv = adS[j * NH + h];
        const float a = (i < NC) ? adjS[i * NC + j] : 0.f;
        const bool msk = (i < NC) && ((i == j) || ((a >= thS[i]) && (a != 0.f)));
        float e = 0.f;
        if (msk) { e = asS[i * 5 + h] + adv; e = e > 0.f ? e : 0.2f * e; }
        float m = msk ? e : -INFINITY;
#pragma unroll
        for (int off = 32; off >= 1; off >>= 1) m = fmaxf(m, __shfl_xor(m, off));
        const float p = msk ? __expf(e - m) : 0.f;
        float s = p;
#pragma unroll
        for (int off = 32; off >= 1; off >>= 1) s += __shfl_xor(s, off);
        wS[(h << 6) + l] = p / s;
    }
    __syncthreads();

    const int q = t >> 8, col = t & 255;
    float acc = 0.f;
    const float* hpc = hp + col;
#pragma unroll 8
    for (int e = q * 128; e < q * 128 + 128; ++e)
        acc += wS[e] * hpc[(size_t)e * 256];
    psum[q][col] = acc;
    __syncthreads();
    if (t < ND) out[(size_t)j * ND + t] = psum[0][t] + psum[1][t] + biasc[t];
}

// ============================================================================
// k_wc_part (unchanged)
// ============================================================================
__global__ __launch_bounds__(256) void k_wc_part(const float* __restrict__ Wg,
                                                 const float* __restrict__ bias_gat,
                                                 const float* __restrict__ Wp,
                                                 float* __restrict__ pWcT,
                                                 float* __restrict__ pbias) {
    __shared__ float rows[250];
    const int b = blockIdx.x, t = threadIdx.x;
    if (b < 1000) {
        const int fb = (b >> 3) * 2, kq = b & 7;
        if (t < 250)
            rows[t] = Wg[(size_t)(fb + t / 125) * NHD + kq * 125 + (t % 125)];
        __syncthreads();
        if (t < ND) {
            float a0 = 0.f, a1 = 0.f;
            const float* wp = Wp + (size_t)(kq * 125) * ND + t;
            for (int k = 0; k < 125; ++k) {
                float wv = wp[(size_t)k * ND];
                a0 += rows[k] * wv;
                a1 += rows[125 + k] * wv;
            }
            pWcT[(size_t)kq * 65536 + (size_t)t * 256 + fb] = a0;
            pWcT[(size_t)kq * 65536 + (size_t)t * 256 + fb + 1] = a1;
        }
    } else {
        const int kq = b - 1000;
        if (t < ND) {
            float acc = 0.f;
            for (int k = kq * 125; k < kq * 125 + 125; ++k)
                acc += bias_gat[k] * Wp[(size_t)k * ND + t];
            pbias[kq * 256 + t] = acc;
        }
    }
}

// ============================================================================
// k_wct (unchanged)
// ============================================================================
__global__ __launch_bounds__(256) void k_wct(const float* __restrict__ pWcT,
                                             const float* __restrict__ pbias,
                                             const float* __restrict__ b_proj,
                                             __bf16* __restrict__ WcT,
                                             __bf16* __restrict__ WchT,
                                             float* __restrict__ biasc) {
    const int n = blockIdx.x, t = threadIdx.x;
    if (n < 256) {
        float v[8];
        float tot = 0.f;
#pragma unroll
        for (int kq = 0; kq < 8; ++kq) {
            float xv = 0.f;
            if (n < ND && t < NF) xv = pWcT[(size_t)kq * 65536 + (size_t)n * 256 + t];
            v[kq] = xv; tot += xv;
        }
        WcT[n * 256 + t] = (__bf16)tot;
#pragma unroll
        for (int h = 0; h < NH; ++h)
            WchT[h * 65536 + n * 256 + t] = (__bf16)(v[2 * h] + v[2 * h + 1]);
    } else {
        if (t < ND) {
            float v = 0.f;
#pragma unroll
            for (int kq = 0; kq < 8; ++kq) v += pbias[kq * 256 + t];
            biasc[t] = v + b_proj[t];
        }
    }
}

// ============================================================================
// k_hp (unchanged)
// ============================================================================
__global__ __launch_bounds__(256) void k_hp(const float* __restrict__ x,
                                            const __bf16* __restrict__ WchT,
                                            float* __restrict__ hp) {
    __shared__ __align__(16) __bf16 Xs[64 * 256];
    const int h = blockIdx.x;
    const int t = threadIdx.x;
    const int w = t >> 6, l = t & 63;
    const int l16 = l & 15, lq = l >> 4;
    const int nb = w * 64;
    const int swz = (l16 & 7) << 3;

    bf16x8 bfr[4][8];
    const __bf16* Wh = WchT + h * 65536;
#pragma unroll
    for (int ni = 0; ni < 4; ++ni) {
        const int n = nb + ni * 16 + l16;
#pragma unroll
        for (int kc = 0; kc < 8; ++kc)
            bfr[ni][kc] = *(const bf16x8*)(Wh + (size_t)n * 256 + kc * 32 + lq * 8);
    }

#pragma unroll
    for (int it = 0; it < 8; ++it) {
        const int u = it * 256 + t;
        const int row = u >> 5;
        const int ko = (u & 31) << 3;
        float v[8];
#pragma unroll
        for (int q = 0; q < 4; ++q) { v[2 * q] = 0.f; v[2 * q + 1] = 0.f; }
        if (row < NC) {
            const float* src = x + row * NF + ko;
#pragma unroll
            for (int q = 0; q < 4; ++q) {
                if (ko + 2 * q + 1 < NF) {
                    const float2 p = *(const float2*)(src + 2 * q);
                    v[2 * q] = p.x; v[2 * q + 1] = p.y;
                }
            }
        }
        bf16x8 hv;
#pragma unroll
        for (int jj = 0; jj < 8; ++jj) hv[jj] = (__bf16)v[jj];
        *(bf16x8*)&Xs[row * 256 + (ko ^ ((row & 7) << 3))] = hv;
    }
    __syncthreads();

    f32x4 acc[4][4];
    const f32x4 z4 = {0.f, 0.f, 0.f, 0.f};
#pragma unroll
    for (int mi = 0; mi < 4; ++mi)
#pragma unroll
        for (int ni = 0; ni < 4; ++ni) acc[mi][ni] = z4;

#pragma unroll
    for (int kc = 0; kc < 8; ++kc) {
        const int kb = (kc * 32 + lq * 8) ^ swz;
        bf16x8 afr[4];
#pragma unroll
        for (int mi = 0; mi < 4; ++mi)
            afr[mi] = *(const bf16x8*)&Xs[(mi * 16 + l16) * 256 + kb];
#pragma unroll
        for (int mi = 0; mi < 4; ++mi)
#pragma unroll
            for (int ni = 0; ni < 4; ++ni)
                acc[mi][ni] = __builtin_amdgcn_mfma_f32_16x16x32_bf16(
                    afr[mi], bfr[ni][kc], acc[mi][ni], 0, 0, 0);
    }

#pragma unroll
    for (int mi = 0; mi < 4; ++mi)
#pragma unroll
        for (int r = 0; r < 4; ++r) {
            const int row = mi * 16 + lq * 4 + r;
#pragma unroll
            for (int ni = 0; ni < 4; ++ni) {
                const int col = nb + ni * 16 + l16;
                hp[(size_t)(h * 64 + row) * 256 + col] = acc[mi][ni][r];
            }
        }
}

// ============================================================================
extern "C" void kernel_launch(void* const* d_in, const int* in_sizes, int n_in,
                              void* d_out, int out_size, void* d_ws, size_t ws_size,
                              hipStream_t stream) {
    const float* x       = (const float*)d_in[0];
    const float* Wg      = (const float*)d_in[1];
    const float* att_src = (const float*)d_in[2];
    const float* att_dst = (const float*)d_in[3];
    const float* bias_g  = (const float*)d_in[4];
    const float* Wp      = (const float*)d_in[5];
    const float* b_proj  = (const float*)d_in[6];
    float* out = (float*)d_out;
    float* ws  = (float*)d_ws;

    __bf16* WcT    = (__bf16*)ws;                 // 65536 bf16  = 32768 f
    __bf16* WchT   = (__bf16*)(ws + 32768);       // 4*65536 bf16 = 131072 f
    float* pWcT    = ws + 32768 + 131072;         // 8*65536 = 524288
    float* pbias   = pWcT + 8 * 65536;            // 2048
    float* biasc   = pbias + 2048;                // 256
    float* partial = biasc + 256;                 // 1024*4096 = 4,194,304
    float* adj     = partial + 1024 * 4096;       // 3969
    float* hp      = adj + NC * NC;               // 256*256 = 65536
    float* gs      = hp + 65536;                  // 1000
    float* gd      = gs + 1000;                   // 1000
    float* as_     = gd + 1000;                   // 252
    float* ad_     = as_ + 252;                   // 252
    float* abl     = ad_ + 252;                   // 1024*256 = 262144 (~20.7 MB total)

    k_wc_part<<<1008, 256, 0, stream>>>(Wg, bias_g, Wp, pWcT, pbias);
    k_wct<<<257, 256, 0, stream>>>(pWcT, pbias, b_proj, WcT, WchT, biasc);
    k_fused<<<1024, 256, 0, stream>>>(x, WcT, biasc, out, partial);
    k_adj_reduce<<<63, 512, 0, stream>>>(partial, adj);
    k_gs<<<250, 256, 0, stream>>>(Wg, att_src, att_dst, gs, gd);
    k_asad<<<1, 512, 0, stream>>>(x, gs, gd, as_, ad_);
    k_hp<<<4, 256, 0, stream>>>(x, WchT, hp);
    k_out0<<<63, 512, 0, stream>>>(adj, as_, ad_, hp, biasc, out);
    // ---- diagnostics (outputs unaffected) ----
    k_abl<1><<<1024, 256, 0, stream>>>(x, WcT, abl);
    k_abl<2><<<1024, 256, 0, stream>>>(x, WcT, abl);
}

// Round 16
// 163.441 us; speedup vs baseline: 2.3839x; 2.3839x over previous
//
#include <hip/hip_runtime.h>
#include <math.h>

#define NB 1024
#define NC 63
#define NF 250
#define NH 4
#define ND 250
#define NHD 1000

typedef __bf16 bf16x8 __attribute__((ext_vector_type(8)));
typedef float f32x4 __attribute__((ext_vector_type(4)));

// ============================================================================
// k_fused (R12 version, reverted exactly): one batch per block, 64KB LDS.
// 69us measured; balanced {stage~30, compute, epilogue} latency chain.
// ============================================================================
__global__ __launch_bounds__(256) void k_fused(const float* __restrict__ x,
                                               const __bf16* __restrict__ WcT,
                                               const float* __restrict__ biasc,
                                               float* __restrict__ out,
                                               float* __restrict__ partial) {
    __shared__ __align__(16) __bf16 Xh[64 * 256];   // 32 KB (rows 0-1 overlay moments post-compute)
    __shared__ __align__(16) __bf16 Xl[64 * 256];   // 32 KB
    float* const momS = (float*)Xh;  // [0:64)=S [64:128)=SS [128:192)=mean [192:256)=scl
    const int t = threadIdx.x;
    const int w = t >> 6, l = t & 63;
    const int l16 = l & 15, lq = l >> 4;
    const int swz = (l16 & 7) << 3;
    const int nb = w * 64;

    {
        const int kz = t ^ 56;                 // (63&7)<<3
        Xh[63 * 256 + kz] = (__bf16)1.0f;
        Xl[63 * 256 + kz] = (__bf16)0.0f;
    }

    float bc[4];
#pragma unroll
    for (int ni = 0; ni < 4; ++ni) {
        const int col = nb + ni * 16 + l16;
        bc[ni] = (col < ND) ? biasc[col] : 0.f;
    }

    const f32x4 z4 = {0.f, 0.f, 0.f, 0.f};
    const int b = blockIdx.x;
    const float* xb = x + (size_t)b * (NC * NF);

    // ---- stage: 63 rows x 32 octets, coalesced float2 -> hi/lo bf16
#pragma unroll
    for (int it = 0; it < 8; ++it) {
        const int u = it * 256 + t;
        if (u < 2016) {
            const int row = u >> 5;
            const int ko = (u & 31) << 3;
            const float* src = xb + row * NF + ko;
            float v[8];
#pragma unroll
            for (int q = 0; q < 4; ++q) {
                if (ko + q * 2 < NF) {
                    const float2 p = *(const float2*)(src + q * 2);
                    v[2 * q] = p.x; v[2 * q + 1] = p.y;
                } else { v[2 * q] = 0.f; v[2 * q + 1] = 0.f; }
            }
            bf16x8 h, lo_;
#pragma unroll
            for (int j = 0; j < 8; ++j) {
                h[j] = (__bf16)v[j];
                lo_[j] = (__bf16)(v[j] - (float)h[j]);
            }
            const int kS = ko ^ ((row & 7) << 3);
            *(bf16x8*)&Xh[row * 256 + kS] = h;
            *(bf16x8*)&Xl[row * 256 + kS] = lo_;
        }
    }
    __syncthreads();   // staging complete

    bf16x8 bfr[4][4];
    f32x4 accM[4][4];
    f32x4 accG[4];
#pragma unroll
    for (int mi = 0; mi < 4; ++mi)
#pragma unroll
        for (int ni = 0; ni < 4; ++ni) accM[mi][ni] = z4;
#pragma unroll
    for (int ni = 0; ni < 4; ++ni) accG[ni] = z4;

    const int garow = (16 * w + l16) * 256;   // gram A row base

    // ================= K half 0 (kc 0..3) =================
#pragma unroll
    for (int ni = 0; ni < 4; ++ni) {
        const int n = nb + ni * 16 + l16;
#pragma unroll
        for (int kk = 0; kk < 4; ++kk)
            bfr[ni][kk] = *(const bf16x8*)(WcT + (size_t)n * 256 + kk * 32 + lq * 8);
    }
#pragma unroll
    for (int kk = 0; kk < 4; ++kk) {
        const int kb = (kk * 32 + lq * 8) ^ swz;
        bf16x8 hi[4], lo[4];
#pragma unroll
        for (int r = 0; r < 4; ++r) {
            hi[r] = *(const bf16x8*)&Xh[(r * 16 + l16) * 256 + kb];
            lo[r] = *(const bf16x8*)&Xl[(r * 16 + l16) * 256 + kb];
        }
        const bf16x8 ah = *(const bf16x8*)&Xh[garow + kb];
        const bf16x8 al = *(const bf16x8*)&Xl[garow + kb];
#pragma unroll
        for (int mi = 0; mi < 4; ++mi)
#pragma unroll
            for (int ni = 0; ni < 4; ++ni)
                accM[mi][ni] = __builtin_amdgcn_mfma_f32_16x16x32_bf16(
                    hi[mi], bfr[ni][kk], accM[mi][ni], 0, 0, 0);
#pragma unroll
        for (int ni = 0; ni < 4; ++ni) {
            accG[ni] = __builtin_amdgcn_mfma_f32_16x16x32_bf16(ah, hi[ni], accG[ni], 0, 0, 0);
            accG[ni] = __builtin_amdgcn_mfma_f32_16x16x32_bf16(ah, lo[ni], accG[ni], 0, 0, 0);
            accG[ni] = __builtin_amdgcn_mfma_f32_16x16x32_bf16(al, hi[ni], accG[ni], 0, 0, 0);
        }
    }

    // ================= K half 1 (kc 4..7) =================
#pragma unroll
    for (int ni = 0; ni < 4; ++ni) {
        const int n = nb + ni * 16 + l16;
#pragma unroll
        for (int kk = 0; kk < 4; ++kk)
            bfr[ni][kk] = *(const bf16x8*)(WcT + (size_t)n * 256 + (4 + kk) * 32 + lq * 8);
    }
#pragma unroll
    for (int kk = 0; kk < 4; ++kk) {
        const int kb = ((4 + kk) * 32 + lq * 8) ^ swz;
        bf16x8 hi[4], lo[4];
#pragma unroll
        for (int r = 0; r < 4; ++r) {
            hi[r] = *(const bf16x8*)&Xh[(r * 16 + l16) * 256 + kb];
            lo[r] = *(const bf16x8*)&Xl[(r * 16 + l16) * 256 + kb];
        }
        const bf16x8 ah = *(const bf16x8*)&Xh[garow + kb];
        const bf16x8 al = *(const bf16x8*)&Xl[garow + kb];
#pragma unroll
        for (int mi = 0; mi < 4; ++mi)
#pragma unroll
            for (int ni = 0; ni < 4; ++ni)
                accM[mi][ni] = __builtin_amdgcn_mfma_f32_16x16x32_bf16(
                    hi[mi], bfr[ni][kk], accM[mi][ni], 0, 0, 0);
#pragma unroll
        for (int ni = 0; ni < 4; ++ni) {
            accG[ni] = __builtin_amdgcn_mfma_f32_16x16x32_bf16(ah, hi[ni], accG[ni], 0, 0, 0);
            accG[ni] = __builtin_amdgcn_mfma_f32_16x16x32_bf16(ah, lo[ni], accG[ni], 0, 0, 0);
            accG[ni] = __builtin_amdgcn_mfma_f32_16x16x32_bf16(al, hi[ni], accG[ni], 0, 0, 0);
        }
    }

    __syncthreads();   // ALL plane reads done before overlay write (alias hazard)

    if (l16 == 15) {
#pragma unroll
        for (int r = 0; r < 4; ++r) momS[16 * w + lq * 4 + r] = accG[3][r];
    }
    if ((l16 >> 2) == lq) momS[64 + 16 * w + l16] = accG[w][l16 & 3];
    __syncthreads();
    if (t < 64) {
        const float S = momS[t], SSv = momS[64 + t];
        float m = S * (1.f / (float)NF);
        const float var = (SSv - S * S * (1.f / (float)NF)) * (1.f / (float)(NF - 1));
        float sc = 1.f / (sqrtf(var) + 1e-8f);
        if (t >= NC) { m = 0.f; sc = 0.f; }
        momS[128 + t] = m; momS[192 + t] = sc;
    }
    __syncthreads();

    float mr[4], sr[4];
#pragma unroll
    for (int r = 0; r < 4; ++r) {
        const int row = 16 * w + lq * 4 + r;
        mr[r] = momS[128 + row]; sr[r] = momS[192 + row];
    }
#pragma unroll
    for (int ni = 0; ni < 4; ++ni) {
        const float mc = momS[128 + 16 * ni + l16];
        const float sc = momS[192 + 16 * ni + l16];
#pragma unroll
        for (int r = 0; r < 4; ++r) {
            const int row = 16 * w + lq * 4 + r;
            const int col = 16 * ni + l16;
            partial[(size_t)b * 4096 + row * 64 + col] =
                (accG[ni][r] - (float)NF * mr[r] * mc) * sr[r] * sc;
        }
    }

    const size_t ob = (size_t)b * NC;
#pragma unroll
    for (int mi = 0; mi < 4; ++mi) {
#pragma unroll
        for (int r = 0; r < 4; ++r) {
            const int rt = mi * 16 + lq * 4 + r;
            if (rt < NC) {
#pragma unroll
                for (int ni = 0; ni < 4; ++ni) {
                    const int col = nb + ni * 16 + l16;
                    if (col < ND)
                        out[(ob + rt) * ND + col] = accM[mi][ni][r] + bc[ni];
                }
            }
        }
    }
}

// ============================================================================
// k_gswc = k_wc_part UNION k_gs (both stream Wg; gs is input-independent).
// blocks 0..999: Wc split-K partials; 1000..1007: pbias; 1008..1257: gs/gd.
// ============================================================================
__global__ __launch_bounds__(256) void k_gswc(const float* __restrict__ Wg,
                                              const float* __restrict__ att_src,
                                              const float* __restrict__ att_dst,
                                              const float* __restrict__ bias_gat,
                                              const float* __restrict__ Wp,
                                              float* __restrict__ pWcT,
                                              float* __restrict__ pbias,
                                              float* __restrict__ gs,
                                              float* __restrict__ gd) {
    __shared__ float rows[250];
    const int b = blockIdx.x, t = threadIdx.x;
    if (b < 1000) {
        const int fb = (b >> 3) * 2, kq = b & 7;
        if (t < 250)
            rows[t] = Wg[(size_t)(fb + t / 125) * NHD + kq * 125 + (t % 125)];
        __syncthreads();
        if (t < ND) {
            float a0 = 0.f, a1 = 0.f;
            const float* wp = Wp + (size_t)(kq * 125) * ND + t;
            for (int k = 0; k < 125; ++k) {
                float wv = wp[(size_t)k * ND];
                a0 += rows[k] * wv;
                a1 += rows[125 + k] * wv;
            }
            pWcT[(size_t)kq * 65536 + (size_t)t * 256 + fb] = a0;
            pWcT[(size_t)kq * 65536 + (size_t)t * 256 + fb + 1] = a1;
        }
    } else if (b < 1008) {
        const int kq = b - 1000;
        if (t < ND) {
            float acc = 0.f;
            for (int k = kq * 125; k < kq * 125 + 125; ++k)
                acc += bias_gat[k] * Wp[(size_t)k * ND + t];
            pbias[kq * 256 + t] = acc;
        }
    } else {
        const int f = b - 1008;
        const int h = t >> 6, l = t & 63;
        const float* wr = Wg + (size_t)f * NHD + h * ND;
        const float* sp = att_src + h * ND;
        const float* dp = att_dst + h * ND;
        float s = 0.f, d = 0.f;
#pragma unroll
        for (int q = 0; q < 4; ++q) {
            const int dd = l + q * 64;
            if (dd < ND) {
                const float wv = wr[dd];
                s += wv * sp[dd];
                d += wv * dp[dd];
            }
        }
#pragma unroll
        for (int off = 32; off >= 1; off >>= 1) {
            s += __shfl_down(s, off);
            d += __shfl_down(d, off);
        }
        if (l == 0) { gs[f * NH + h] = s; gd[f * NH + h] = d; }
    }
}

// ============================================================================
// k_wcthp = k_wct UNION k_hp. WchT eliminated: hp builds B-fragments from
// pWcT pair-sums inline (bit-identical bf16(v[2h]+v[2h+1]) rounding).
// blocks 0..255: WcT combine; 256: biasc; 257..260: hp head h=b-257.
// ============================================================================
__global__ __launch_bounds__(256) void k_wcthp(const float* __restrict__ pWcT,
                                               const float* __restrict__ pbias,
                                               const float* __restrict__ b_proj,
                                               const float* __restrict__ x,
                                               __bf16* __restrict__ WcT,
                                               float* __restrict__ biasc,
                                               float* __restrict__ hp) {
    __shared__ __align__(16) __bf16 Xs[64 * 256];
    const int bidx = blockIdx.x, t = threadIdx.x;
    if (bidx < 256) {
        const int n = bidx;
        float tot = 0.f;
        if (n < ND && t < NF) {
            size_t e = (size_t)n * 256 + t;
#pragma unroll
            for (int kq = 0; kq < 8; ++kq) tot += pWcT[(size_t)kq * 65536 + e];
        }
        WcT[n * 256 + t] = (__bf16)tot;
    } else if (bidx == 256) {
        if (t < ND) {
            float v = 0.f;
#pragma unroll
            for (int kq = 0; kq < 8; ++kq) v += pbias[kq * 256 + t];
            biasc[t] = v + b_proj[t];
        }
    } else {
        const int h = bidx - 257;
        const int w = t >> 6, l = t & 63;
        const int l16 = l & 15, lq = l >> 4;
        const int nb = w * 64;
        const int swz = (l16 & 7) << 3;
        const float* p0 = pWcT + (size_t)(2 * h) * 65536;
        const float* p1 = pWcT + (size_t)(2 * h + 1) * 65536;

        // B fragments from pWcT pair sums (rows n>=ND / cols f>=NF are 0 in pWcT? 
        // pWcT only written for t<ND,f<NF -> unwritten region is garbage; but
        // fragments only index n<256 and f<256 where n=nb+ni*16+l16<=255 and
        // f=kc*32+lq*8+j<=255. Guard: zero out-of-range explicitly.
        bf16x8 bfr[4][8];
#pragma unroll
        for (int ni = 0; ni < 4; ++ni) {
            const int n = nb + ni * 16 + l16;
#pragma unroll
            for (int kc = 0; kc < 8; ++kc) {
                const size_t base = (size_t)n * 256 + kc * 32 + lq * 8;
                bf16x8 r;
#pragma unroll
                for (int j = 0; j < 8; ++j) {
                    const int f = kc * 32 + lq * 8 + j;
                    float v = 0.f;
                    if (n < ND && f < NF) v = p0[base + j] + p1[base + j];
                    r[j] = (__bf16)v;
                }
                bfr[ni][kc] = r;
            }
        }

        // stage x0 (rows 0..62, row 63 zero)
#pragma unroll
        for (int it = 0; it < 8; ++it) {
            const int u = it * 256 + t;
            const int row = u >> 5;
            const int ko = (u & 31) << 3;
            float v[8];
#pragma unroll
            for (int q = 0; q < 4; ++q) { v[2 * q] = 0.f; v[2 * q + 1] = 0.f; }
            if (row < NC) {
                const float* src = x + row * NF + ko;
#pragma unroll
                for (int q = 0; q < 4; ++q) {
                    if (ko + 2 * q + 1 < NF) {
                        const float2 p = *(const float2*)(src + 2 * q);
                        v[2 * q] = p.x; v[2 * q + 1] = p.y;
                    }
                }
            }
            bf16x8 hv;
#pragma unroll
            for (int jj = 0; jj < 8; ++jj) hv[jj] = (__bf16)v[jj];
            *(bf16x8*)&Xs[row * 256 + (ko ^ ((row & 7) << 3))] = hv;
        }
        __syncthreads();

        f32x4 acc[4][4];
        const f32x4 z4 = {0.f, 0.f, 0.f, 0.f};
#pragma unroll
        for (int mi = 0; mi < 4; ++mi)
#pragma unroll
            for (int ni = 0; ni < 4; ++ni) acc[mi][ni] = z4;

#pragma unroll
        for (int kc = 0; kc < 8; ++kc) {
            const int kb = (kc * 32 + lq * 8) ^ swz;
            bf16x8 afr[4];
#pragma unroll
            for (int mi = 0; mi < 4; ++mi)
                afr[mi] = *(const bf16x8*)&Xs[(mi * 16 + l16) * 256 + kb];
#pragma unroll
            for (int mi = 0; mi < 4; ++mi)
#pragma unroll
                for (int ni = 0; ni < 4; ++ni)
                    acc[mi][ni] = __builtin_amdgcn_mfma_f32_16x16x32_bf16(
                        afr[mi], bfr[ni][kc], acc[mi][ni], 0, 0, 0);
        }

#pragma unroll
        for (int mi = 0; mi < 4; ++mi)
#pragma unroll
            for (int r = 0; r < 4; ++r) {
                const int row = mi * 16 + lq * 4 + r;
#pragma unroll
                for (int ni = 0; ni < 4; ++ni) {
                    const int col = nb + ni * 16 + l16;
                    hp[(size_t)(h * 64 + row) * 256 + col] = acc[mi][ni][r];
                }
            }
    }
}

// ============================================================================
// k_adjred_asad = k_adj_reduce UNION k_asad. grid 64 x 512.
// blocks 0..62: reduce 1024 partials for adj row; block 63: as_/ad_ dots.
// ============================================================================
__global__ __launch_bounds__(512) void k_adjred_asad(const float* __restrict__ partial,
                                                     const float* __restrict__ x,
                                                     const float* __restrict__ gs,
                                                     const float* __restrict__ gd,
                                                     float* __restrict__ adj,
                                                     float* __restrict__ as_,
                                                     float* __restrict__ ad_) {
    __shared__ float smem[NC * NF + 2 * NHD];   // 71 KB union
    const int t = threadIdx.x;
    if (blockIdx.x < 63) {
        float (*red)[64] = (float(*)[64])smem;
        const int row = blockIdx.x;
        const int c = t & 63, g = t >> 6;
        float s = 0.f;
        const float* p = partial + (size_t)(g * 128) * 4096 + row * 64 + c;
#pragma unroll 8
        for (int i = 0; i < 128; ++i) s += p[(size_t)i * 4096];
        red[g][c] = s;
        __syncthreads();
        if (t < NC) {
            float tot = 0.f;
#pragma unroll
            for (int gg = 0; gg < 8; ++gg) tot += red[gg][t];
            adj[row * NC + t] = tot * (1.f / ((float)NF * (float)NB));
        }
    } else {
        float* x0S = smem;                      // 15750
        float* gsS = smem + NC * NF;            // 1000
        float* gdS = gsS + NHD;                 // 1000
        for (int e = t; e < NC * NF; e += 512) x0S[e] = x[e];
        for (int e = t; e < NF * NH; e += 512) { gsS[e] = gs[e]; gdS[e] = gd[e]; }
        __syncthreads();
        if (t < NC * NH) {
            const int c = t >> 2, h = t & 3;
            float s = 0.f, d = 0.f;
#pragma unroll 5
            for (int f = 0; f < NF; ++f) {
                const float xv = x0S[c * NF + f];
                s += xv * gsS[f * NH + h];
                d += xv * gdS[f * NH + h];
            }
            as_[t] = s; ad_[t] = d;
        }
    }
}

// ============================================================================
// k_out0: register softmax + projection over hp (K=256). (unchanged)
// ============================================================================
__global__ __launch_bounds__(512) void k_out0(const float* __restrict__ adj,
                                              const float* __restrict__ as_,
                                              const float* __restrict__ ad_,
                                              const float* __restrict__ hp,
                                              const float* __restrict__ biasc,
                                              float* __restrict__ out) {
    __shared__ float adjS[NC * NC];
    __shared__ float thS[NC];
    __shared__ float asS[NC * 5];        // stride-5 pad
    __shared__ float adS[NC * NH];
    __shared__ float wS[256];            // w[h*64+i], zeros at i=63
    __shared__ float psum[2][256];
    const int j = blockIdx.x, t = threadIdx.x;
    const int w = t >> 6, l = t & 63;

    for (int e = t; e < NC * NC; e += 512) adjS[e] = adj[e];
    if (t < NC * NH) { asS[(t >> 2) * 5 + (t & 3)] = as_[t]; adS[t] = ad_[t]; }
    __syncthreads();

    for (int r = w; r < NC; r += 8) {
        const float v = (l < NC) ? adjS[r * NC + l] : -INFINITY;
        float prev = INFINITY;
        int krem = 8;                     // TOP_K
        float th = -INFINITY;
#pragma unroll
        for (int iter = 0; iter < 8; ++iter) {
            const float vm = (v < prev) ? v : -INFINITY;
            float m = vm;
#pragma unroll
            for (int off = 32; off >= 1; off >>= 1) m = fmaxf(m, __shfl_xor(m, off));
            const unsigned long long bl = __ballot(vm == m);
            const int cnt = __popcll(bl);
            if (cnt >= krem) { th = m; break; }
            krem -= cnt; prev = m;
        }
        if (l == 0) thS[r] = th;
    }
    __syncthreads();

    if (w < NH) {
        const int h = w, i = l;
        const float adv = adS[j * NH + h];
        const float a = (i < NC) ? adjS[i * NC + j] : 0.f;
        const bool msk = (i < NC) && ((i == j) || ((a >= thS[i]) && (a != 0.f)));
        float e = 0.f;
        if (msk) { e = asS[i * 5 + h] + adv; e = e > 0.f ? e : 0.2f * e; }
        float m = msk ? e : -INFINITY;
#pragma unroll
        for (int off = 32; off >= 1; off >>= 1) m = fmaxf(m, __shfl_xor(m, off));
        const float p = msk ? __expf(e - m) : 0.f;
        float s = p;
#pragma unroll
        for (int off = 32; off >= 1; off >>= 1) s += __shfl_xor(s, off);
        wS[(h << 6) + l] = p / s;        // 0 for i=63 / unmasked
    }
    __syncthreads();

    const int q = t >> 8, col = t & 255;
    float acc = 0.f;
    const float* hpc = hp + col;
#pragma unroll 8
    for (int e = q * 128; e < q * 128 + 128; ++e)
        acc += wS[e] * hpc[(size_t)e * 256];
    psum[q][col] = acc;
    __syncthreads();
    if (t < ND) out[(size_t)j * ND + t] = psum[0][t] + psum[1][t] + biasc[t];
}

// ============================================================================
extern "C" void kernel_launch(void* const* d_in, const int* in_sizes, int n_in,
                              void* d_out, int out_size, void* d_ws, size_t ws_size,
                              hipStream_t stream) {
    const float* x       = (const float*)d_in[0];
    const float* Wg      = (const float*)d_in[1];
    const float* att_src = (const float*)d_in[2];
    const float* att_dst = (const float*)d_in[3];
    const float* bias_g  = (const float*)d_in[4];
    const float* Wp      = (const float*)d_in[5];
    const float* b_proj  = (const float*)d_in[6];
    float* out = (float*)d_out;
    float* ws  = (float*)d_ws;

    __bf16* WcT    = (__bf16*)ws;                 // 65536 bf16 = 32768 f
    float* pWcT    = ws + 32768;                  // 8*65536 = 524288
    float* pbias   = pWcT + 8 * 65536;            // 2048
    float* biasc   = pbias + 2048;                // 256
    float* partial = biasc + 256;                 // 1024*4096 = 4,194,304
    float* adj     = partial + 1024 * 4096;       // 3969
    float* hp      = adj + NC * NC;               // 256*256 = 65536
    float* gs      = hp + 65536;                  // 1000
    float* gd      = gs + 1000;                   // 1000
    float* as_     = gd + 1000;                   // 252
    float* ad_     = as_ + 252;                   // 252  (total ~19.5 MB)

    k_gswc<<<1258, 256, 0, stream>>>(Wg, att_src, att_dst, bias_g, Wp,
                                     pWcT, pbias, gs, gd);
    k_wcthp<<<261, 256, 0, stream>>>(pWcT, pbias, b_proj, x, WcT, biasc, hp);
    k_fused<<<1024, 256, 0, stream>>>(x, WcT, biasc, out, partial);
    k_adjred_asad<<<64, 512, 0, stream>>>(partial, x, gs, gd, adj, as_, ad_);
    k_out0<<<63, 512, 0, stream>>>(adj, as_, ad_, hp, biasc, out);
}

// Round 17
// 120.356 us; speedup vs baseline: 3.2373x; 1.3580x over previous
//
#include <hip/hip_runtime.h>
#include <math.h>

#define NB 1024
#define NC 63
#define NF 250
#define NH 4
#define ND 250
#define NHD 1000

typedef __bf16 bf16x8 __attribute__((ext_vector_type(8)));
typedef float f32x4 __attribute__((ext_vector_type(4)));

// ============================================================================
// k_fused: one batch per block (blocks 0..1023, R12-exact path) PLUS
// 4 hp blocks (1024..1027) = old k_hp reading WchT (vector loads), reusing
// Xh as staging. R16 lesson: hp fragments MUST be 16B vector loads; the
// pWcT pair-sum inlining (512 scalar loads/thread) was a 76us latency chain.
// ============================================================================
__global__ __launch_bounds__(256) void k_fused(const float* __restrict__ x,
                                               const __bf16* __restrict__ WcT,
                                               const __bf16* __restrict__ WchT,
                                               const float* __restrict__ biasc,
                                               float* __restrict__ out,
                                               float* __restrict__ partial,
                                               float* __restrict__ hp) {
    __shared__ __align__(16) __bf16 Xh[64 * 256];   // 32 KB (rows 0-1 overlay moments post-compute)
    __shared__ __align__(16) __bf16 Xl[64 * 256];   // 32 KB (unused by hp blocks)
    float* const momS = (float*)Xh;
    const int t = threadIdx.x;
    const int w = t >> 6, l = t & 63;
    const int l16 = l & 15, lq = l >> 4;
    const int swz = (l16 & 7) << 3;
    const int nb = w * 64;
    const f32x4 z4 = {0.f, 0.f, 0.f, 0.f};

    if (blockIdx.x >= 1024) {
        // ================= hp path (old k_hp, 4 blocks) =================
        const int h = blockIdx.x - 1024;
        bf16x8 bfr[4][8];
        const __bf16* Wh = WchT + h * 65536;
#pragma unroll
        for (int ni = 0; ni < 4; ++ni) {
            const int n = nb + ni * 16 + l16;
#pragma unroll
            for (int kc = 0; kc < 8; ++kc)
                bfr[ni][kc] = *(const bf16x8*)(Wh + (size_t)n * 256 + kc * 32 + lq * 8);
        }
#pragma unroll
        for (int it = 0; it < 8; ++it) {
            const int u = it * 256 + t;
            const int row = u >> 5;
            const int ko = (u & 31) << 3;
            float v[8];
#pragma unroll
            for (int q = 0; q < 4; ++q) { v[2 * q] = 0.f; v[2 * q + 1] = 0.f; }
            if (row < NC) {
                const float* src = x + row * NF + ko;
#pragma unroll
                for (int q = 0; q < 4; ++q) {
                    if (ko + 2 * q + 1 < NF) {
                        const float2 p = *(const float2*)(src + 2 * q);
                        v[2 * q] = p.x; v[2 * q + 1] = p.y;
                    }
                }
            }
            bf16x8 hv;
#pragma unroll
            for (int jj = 0; jj < 8; ++jj) hv[jj] = (__bf16)v[jj];
            *(bf16x8*)&Xh[row * 256 + (ko ^ ((row & 7) << 3))] = hv;
        }
        __syncthreads();

        f32x4 acc[4][4];
#pragma unroll
        for (int mi = 0; mi < 4; ++mi)
#pragma unroll
            for (int ni = 0; ni < 4; ++ni) acc[mi][ni] = z4;
#pragma unroll
        for (int kc = 0; kc < 8; ++kc) {
            const int kb = (kc * 32 + lq * 8) ^ swz;
            bf16x8 afr[4];
#pragma unroll
            for (int mi = 0; mi < 4; ++mi)
                afr[mi] = *(const bf16x8*)&Xh[(mi * 16 + l16) * 256 + kb];
#pragma unroll
            for (int mi = 0; mi < 4; ++mi)
#pragma unroll
                for (int ni = 0; ni < 4; ++ni)
                    acc[mi][ni] = __builtin_amdgcn_mfma_f32_16x16x32_bf16(
                        afr[mi], bfr[ni][kc], acc[mi][ni], 0, 0, 0);
        }
#pragma unroll
        for (int mi = 0; mi < 4; ++mi)
#pragma unroll
            for (int r = 0; r < 4; ++r) {
                const int row = mi * 16 + lq * 4 + r;
#pragma unroll
                for (int ni = 0; ni < 4; ++ni) {
                    const int col = nb + ni * 16 + l16;
                    hp[(size_t)(h * 64 + row) * 256 + col] = acc[mi][ni][r];
                }
            }
        return;
    }

    // ================= main+gram path (R12-exact) =================
    {
        const int kz = t ^ 56;                 // (63&7)<<3
        Xh[63 * 256 + kz] = (__bf16)1.0f;
        Xl[63 * 256 + kz] = (__bf16)0.0f;
    }

    float bc[4];
#pragma unroll
    for (int ni = 0; ni < 4; ++ni) {
        const int col = nb + ni * 16 + l16;
        bc[ni] = (col < ND) ? biasc[col] : 0.f;
    }

    const int b = blockIdx.x;
    const float* xb = x + (size_t)b * (NC * NF);

    // ---- stage: 63 rows x 32 octets, coalesced float2 -> hi/lo bf16
#pragma unroll
    for (int it = 0; it < 8; ++it) {
        const int u = it * 256 + t;
        if (u < 2016) {
            const int row = u >> 5;
            const int ko = (u & 31) << 3;
            const float* src = xb + row * NF + ko;
            float v[8];
#pragma unroll
            for (int q = 0; q < 4; ++q) {
                if (ko + q * 2 < NF) {
                    const float2 p = *(const float2*)(src + q * 2);
                    v[2 * q] = p.x; v[2 * q + 1] = p.y;
                } else { v[2 * q] = 0.f; v[2 * q + 1] = 0.f; }
            }
            bf16x8 h, lo_;
#pragma unroll
            for (int j = 0; j < 8; ++j) {
                h[j] = (__bf16)v[j];
                lo_[j] = (__bf16)(v[j] - (float)h[j]);
            }
            const int kS = ko ^ ((row & 7) << 3);
            *(bf16x8*)&Xh[row * 256 + kS] = h;
            *(bf16x8*)&Xl[row * 256 + kS] = lo_;
        }
    }
    __syncthreads();   // staging complete

    bf16x8 bfr[4][4];
    f32x4 accM[4][4];
    f32x4 accG[4];
#pragma unroll
    for (int mi = 0; mi < 4; ++mi)
#pragma unroll
        for (int ni = 0; ni < 4; ++ni) accM[mi][ni] = z4;
#pragma unroll
    for (int ni = 0; ni < 4; ++ni) accG[ni] = z4;

    const int garow = (16 * w + l16) * 256;   // gram A row base

    // ================= K half 0 (kc 0..3) =================
#pragma unroll
    for (int ni = 0; ni < 4; ++ni) {
        const int n = nb + ni * 16 + l16;
#pragma unroll
        for (int kk = 0; kk < 4; ++kk)
            bfr[ni][kk] = *(const bf16x8*)(WcT + (size_t)n * 256 + kk * 32 + lq * 8);
    }
#pragma unroll
    for (int kk = 0; kk < 4; ++kk) {
        const int kb = (kk * 32 + lq * 8) ^ swz;
        bf16x8 hi[4], lo[4];
#pragma unroll
        for (int r = 0; r < 4; ++r) {
            hi[r] = *(const bf16x8*)&Xh[(r * 16 + l16) * 256 + kb];
            lo[r] = *(const bf16x8*)&Xl[(r * 16 + l16) * 256 + kb];
        }
        const bf16x8 ah = *(const bf16x8*)&Xh[garow + kb];
        const bf16x8 al = *(const bf16x8*)&Xl[garow + kb];
#pragma unroll
        for (int mi = 0; mi < 4; ++mi)
#pragma unroll
            for (int ni = 0; ni < 4; ++ni)
                accM[mi][ni] = __builtin_amdgcn_mfma_f32_16x16x32_bf16(
                    hi[mi], bfr[ni][kk], accM[mi][ni], 0, 0, 0);
#pragma unroll
        for (int ni = 0; ni < 4; ++ni) {
            accG[ni] = __builtin_amdgcn_mfma_f32_16x16x32_bf16(ah, hi[ni], accG[ni], 0, 0, 0);
            accG[ni] = __builtin_amdgcn_mfma_f32_16x16x32_bf16(ah, lo[ni], accG[ni], 0, 0, 0);
            accG[ni] = __builtin_amdgcn_mfma_f32_16x16x32_bf16(al, hi[ni], accG[ni], 0, 0, 0);
        }
    }

    // ================= K half 1 (kc 4..7) =================
#pragma unroll
    for (int ni = 0; ni < 4; ++ni) {
        const int n = nb + ni * 16 + l16;
#pragma unroll
        for (int kk = 0; kk < 4; ++kk)
            bfr[ni][kk] = *(const bf16x8*)(WcT + (size_t)n * 256 + (4 + kk) * 32 + lq * 8);
    }
#pragma unroll
    for (int kk = 0; kk < 4; ++kk) {
        const int kb = ((4 + kk) * 32 + lq * 8) ^ swz;
        bf16x8 hi[4], lo[4];
#pragma unroll
        for (int r = 0; r < 4; ++r) {
            hi[r] = *(const bf16x8*)&Xh[(r * 16 + l16) * 256 + kb];
            lo[r] = *(const bf16x8*)&Xl[(r * 16 + l16) * 256 + kb];
        }
        const bf16x8 ah = *(const bf16x8*)&Xh[garow + kb];
        const bf16x8 al = *(const bf16x8*)&Xl[garow + kb];
#pragma unroll
        for (int mi = 0; mi < 4; ++mi)
#pragma unroll
            for (int ni = 0; ni < 4; ++ni)
                accM[mi][ni] = __builtin_amdgcn_mfma_f32_16x16x32_bf16(
                    hi[mi], bfr[ni][kk], accM[mi][ni], 0, 0, 0);
#pragma unroll
        for (int ni = 0; ni < 4; ++ni) {
            accG[ni] = __builtin_amdgcn_mfma_f32_16x16x32_bf16(ah, hi[ni], accG[ni], 0, 0, 0);
            accG[ni] = __builtin_amdgcn_mfma_f32_16x16x32_bf16(ah, lo[ni], accG[ni], 0, 0, 0);
            accG[ni] = __builtin_amdgcn_mfma_f32_16x16x32_bf16(al, hi[ni], accG[ni], 0, 0, 0);
        }
    }

    __syncthreads();   // ALL plane reads done before overlay write (alias hazard)

    if (l16 == 15) {
#pragma unroll
        for (int r = 0; r < 4; ++r) momS[16 * w + lq * 4 + r] = accG[3][r];
    }
    if ((l16 >> 2) == lq) momS[64 + 16 * w + l16] = accG[w][l16 & 3];
    __syncthreads();
    if (t < 64) {
        const float S = momS[t], SSv = momS[64 + t];
        float m = S * (1.f / (float)NF);
        const float var = (SSv - S * S * (1.f / (float)NF)) * (1.f / (float)(NF - 1));
        float sc = 1.f / (sqrtf(var) + 1e-8f);
        if (t >= NC) { m = 0.f; sc = 0.f; }
        momS[128 + t] = m; momS[192 + t] = sc;
    }
    __syncthreads();

    float mr[4], sr[4];
#pragma unroll
    for (int r = 0; r < 4; ++r) {
        const int row = 16 * w + lq * 4 + r;
        mr[r] = momS[128 + row]; sr[r] = momS[192 + row];
    }
#pragma unroll
    for (int ni = 0; ni < 4; ++ni) {
        const float mc = momS[128 + 16 * ni + l16];
        const float sc = momS[192 + 16 * ni + l16];
#pragma unroll
        for (int r = 0; r < 4; ++r) {
            const int row = 16 * w + lq * 4 + r;
            const int col = 16 * ni + l16;
            partial[(size_t)b * 4096 + row * 64 + col] =
                (accG[ni][r] - (float)NF * mr[r] * mc) * sr[r] * sc;
        }
    }

    const size_t ob = (size_t)b * NC;
#pragma unroll
    for (int mi = 0; mi < 4; ++mi) {
#pragma unroll
        for (int r = 0; r < 4; ++r) {
            const int rt = mi * 16 + lq * 4 + r;
            if (rt < NC) {
#pragma unroll
                for (int ni = 0; ni < 4; ++ni) {
                    const int col = nb + ni * 16 + l16;
                    if (col < ND)
                        out[(ob + rt) * ND + col] = accM[mi][ni][r] + bc[ni];
                }
            }
        }
    }
}

// ============================================================================
// k_gswc = k_wc_part UNION k_gs. (unchanged from R16)
// ============================================================================
__global__ __launch_bounds__(256) void k_gswc(const float* __restrict__ Wg,
                                              const float* __restrict__ att_src,
                                              const float* __restrict__ att_dst,
                                              const float* __restrict__ bias_gat,
                                              const float* __restrict__ Wp,
                                              float* __restrict__ pWcT,
                                              float* __restrict__ pbias,
                                              float* __restrict__ gs,
                                              float* __restrict__ gd) {
    __shared__ float rows[250];
    const int b = blockIdx.x, t = threadIdx.x;
    if (b < 1000) {
        const int fb = (b >> 3) * 2, kq = b & 7;
        if (t < 250)
            rows[t] = Wg[(size_t)(fb + t / 125) * NHD + kq * 125 + (t % 125)];
        __syncthreads();
        if (t < ND) {
            float a0 = 0.f, a1 = 0.f;
            const float* wp = Wp + (size_t)(kq * 125) * ND + t;
            for (int k = 0; k < 125; ++k) {
                float wv = wp[(size_t)k * ND];
                a0 += rows[k] * wv;
                a1 += rows[125 + k] * wv;
            }
            pWcT[(size_t)kq * 65536 + (size_t)t * 256 + fb] = a0;
            pWcT[(size_t)kq * 65536 + (size_t)t * 256 + fb + 1] = a1;
        }
    } else if (b < 1008) {
        const int kq = b - 1000;
        if (t < ND) {
            float acc = 0.f;
            for (int k = kq * 125; k < kq * 125 + 125; ++k)
                acc += bias_gat[k] * Wp[(size_t)k * ND + t];
            pbias[kq * 256 + t] = acc;
        }
    } else {
        const int f = b - 1008;
        const int h = t >> 6, l = t & 63;
        const float* wr = Wg + (size_t)f * NHD + h * ND;
        const float* sp = att_src + h * ND;
        const float* dp = att_dst + h * ND;
        float s = 0.f, d = 0.f;
#pragma unroll
        for (int q = 0; q < 4; ++q) {
            const int dd = l + q * 64;
            if (dd < ND) {
                const float wv = wr[dd];
                s += wv * sp[dd];
                d += wv * dp[dd];
            }
        }
#pragma unroll
        for (int off = 32; off >= 1; off >>= 1) {
            s += __shfl_down(s, off);
            d += __shfl_down(d, off);
        }
        if (l == 0) { gs[f * NH + h] = s; gd[f * NH + h] = d; }
    }
}

// ============================================================================
// k_wct (R12 version restored): WcT + per-head WchT bf16 + biasc. grid 257.
// ============================================================================
__global__ __launch_bounds__(256) void k_wct(const float* __restrict__ pWcT,
                                             const float* __restrict__ pbias,
                                             const float* __restrict__ b_proj,
                                             __bf16* __restrict__ WcT,
                                             __bf16* __restrict__ WchT,
                                             float* __restrict__ biasc) {
    const int n = blockIdx.x, t = threadIdx.x;
    if (n < 256) {
        float v[8];
        float tot = 0.f;
#pragma unroll
        for (int kq = 0; kq < 8; ++kq) {
            float xv = 0.f;
            if (n < ND && t < NF) xv = pWcT[(size_t)kq * 65536 + (size_t)n * 256 + t];
            v[kq] = xv; tot += xv;
        }
        WcT[n * 256 + t] = (__bf16)tot;
#pragma unroll
        for (int h = 0; h < NH; ++h)
            WchT[h * 65536 + n * 256 + t] = (__bf16)(v[2 * h] + v[2 * h + 1]);
    } else {
        if (t < ND) {
            float v = 0.f;
#pragma unroll
            for (int kq = 0; kq < 8; ++kq) v += pbias[kq * 256 + t];
            biasc[t] = v + b_proj[t];
        }
    }
}

// ============================================================================
// k_adjred_asad = k_adj_reduce UNION k_asad. grid 64 x 512. (unchanged)
// ============================================================================
__global__ __launch_bounds__(512) void k_adjred_asad(const float* __restrict__ partial,
                                                     const float* __restrict__ x,
                                                     const float* __restrict__ gs,
                                                     const float* __restrict__ gd,
                                                     float* __restrict__ adj,
                                                     float* __restrict__ as_,
                                                     float* __restrict__ ad_) {
    __shared__ float smem[NC * NF + 2 * NHD];   // 71 KB union
    const int t = threadIdx.x;
    if (blockIdx.x < 63) {
        float (*red)[64] = (float(*)[64])smem;
        const int row = blockIdx.x;
        const int c = t & 63, g = t >> 6;
        float s = 0.f;
        const float* p = partial + (size_t)(g * 128) * 4096 + row * 64 + c;
#pragma unroll 8
        for (int i = 0; i < 128; ++i) s += p[(size_t)i * 4096];
        red[g][c] = s;
        __syncthreads();
        if (t < NC) {
            float tot = 0.f;
#pragma unroll
            for (int gg = 0; gg < 8; ++gg) tot += red[gg][t];
            adj[row * NC + t] = tot * (1.f / ((float)NF * (float)NB));
        }
    } else {
        float* x0S = smem;                      // 15750
        float* gsS = smem + NC * NF;            // 1000
        float* gdS = gsS + NHD;                 // 1000
        for (int e = t; e < NC * NF; e += 512) x0S[e] = x[e];
        for (int e = t; e < NF * NH; e += 512) { gsS[e] = gs[e]; gdS[e] = gd[e]; }
        __syncthreads();
        if (t < NC * NH) {
            const int c = t >> 2, h = t & 3;
            float s = 0.f, d = 0.f;
#pragma unroll 5
            for (int f = 0; f < NF; ++f) {
                const float xv = x0S[c * NF + f];
                s += xv * gsS[f * NH + h];
                d += xv * gdS[f * NH + h];
            }
            as_[t] = s; ad_[t] = d;
        }
    }
}

// ============================================================================
// k_out0: register softmax + projection over hp (K=256). (unchanged)
// ============================================================================
__global__ __launch_bounds__(512) void k_out0(const float* __restrict__ adj,
                                              const float* __restrict__ as_,
                                              const float* __restrict__ ad_,
                                              const float* __restrict__ hp,
                                              const float* __restrict__ biasc,
                                              float* __restrict__ out) {
    __shared__ float adjS[NC * NC];
    __shared__ float thS[NC];
    __shared__ float asS[NC * 5];        // stride-5 pad
    __shared__ float adS[NC * NH];
    __shared__ float wS[256];            // w[h*64+i], zeros at i=63
    __shared__ float psum[2][256];
    const int j = blockIdx.x, t = threadIdx.x;
    const int w = t >> 6, l = t & 63;

    for (int e = t; e < NC * NC; e += 512) adjS[e] = adj[e];
    if (t < NC * NH) { asS[(t >> 2) * 5 + (t & 3)] = as_[t]; adS[t] = ad_[t]; }
    __syncthreads();

    for (int r = w; r < NC; r += 8) {
        const float v = (l < NC) ? adjS[r * NC + l] : -INFINITY;
        float prev = INFINITY;
        int krem = 8;                     // TOP_K
        float th = -INFINITY;
#pragma unroll
        for (int iter = 0; iter < 8; ++iter) {
            const float vm = (v < prev) ? v : -INFINITY;
            float m = vm;
#pragma unroll
            for (int off = 32; off >= 1; off >>= 1) m = fmaxf(m, __shfl_xor(m, off));
            const unsigned long long bl = __ballot(vm == m);
            const int cnt = __popcll(bl);
            if (cnt >= krem) { th = m; break; }
            krem -= cnt; prev = m;
        }
        if (l == 0) thS[r] = th;
    }
    __syncthreads();

    if (w < NH) {
        const int h = w, i = l;
        const float adv = adS[j * NH + h];
        const float a = (i < NC) ? adjS[i * NC + j] : 0.f;
        const bool msk = (i < NC) && ((i == j) || ((a >= thS[i]) && (a != 0.f)));
        float e = 0.f;
        if (msk) { e = asS[i * 5 + h] + adv; e = e > 0.f ? e : 0.2f * e; }
        float m = msk ? e : -INFINITY;
#pragma unroll
        for (int off = 32; off >= 1; off >>= 1) m = fmaxf(m, __shfl_xor(m, off));
        const float p = msk ? __expf(e - m) : 0.f;
        float s = p;
#pragma unroll
        for (int off = 32; off >= 1; off >>= 1) s += __shfl_xor(s, off);
        wS[(h << 6) + l] = p / s;        // 0 for i=63 / unmasked
    }
    __syncthreads();

    const int q = t >> 8, col = t & 255;
    float acc = 0.f;
    const float* hpc = hp + col;
#pragma unroll 8
    for (int e = q * 128; e < q * 128 + 128; ++e)
        acc += wS[e] * hpc[(size_t)e * 256];
    psum[q][col] = acc;
    __syncthreads();
    if (t < ND) out[(size_t)j * ND + t] = psum[0][t] + psum[1][t] + biasc[t];
}

// ============================================================================
extern "C" void kernel_launch(void* const* d_in, const int* in_sizes, int n_in,
                              void* d_out, int out_size, void* d_ws, size_t ws_size,
                              hipStream_t stream) {
    const float* x       = (const float*)d_in[0];
    const float* Wg      = (const float*)d_in[1];
    const float* att_src = (const float*)d_in[2];
    const float* att_dst = (const float*)d_in[3];
    const float* bias_g  = (const float*)d_in[4];
    const float* Wp      = (const float*)d_in[5];
    const float* b_proj  = (const float*)d_in[6];
    float* out = (float*)d_out;
    float* ws  = (float*)d_ws;

    __bf16* WcT    = (__bf16*)ws;                 // 65536 bf16  = 32768 f
    __bf16* WchT   = (__bf16*)(ws + 32768);       // 4*65536 bf16 = 131072 f
    float* pWcT    = ws + 32768 + 131072;         // 8*65536 = 524288
    float* pbias   = pWcT + 8 * 65536;            // 2048
    float* biasc   = pbias + 2048;                // 256
    float* partial = biasc + 256;                 // 1024*4096 = 4,194,304
    float* adj     = partial + 1024 * 4096;       // 3969
    float* hp      = adj + NC * NC;               // 256*256 = 65536
    float* gs      = hp + 65536;                  // 1000
    float* gd      = gs + 1000;                   // 1000
    float* as_     = gd + 1000;                   // 252
    float* ad_     = as_ + 252;                   // 252  (total ~19.7 MB)

    k_gswc<<<1258, 256, 0, stream>>>(Wg, att_src, att_dst, bias_g, Wp,
                                     pWcT, pbias, gs, gd);
    k_wct<<<257, 256, 0, stream>>>(pWcT, pbias, b_proj, WcT, WchT, biasc);
    k_fused<<<1028, 256, 0, stream>>>(x, WcT, WchT, biasc, out, partial, hp);
    k_adjred_asad<<<64, 512, 0, stream>>>(partial, x, gs, gd, adj, as_, ad_);
    k_out0<<<63, 512, 0, stream>>>(adj, as_, ad_, hp, biasc, out);
}

// Round 18
// 100.622 us; speedup vs baseline: 3.8722x; 1.1961x over previous
//
#include <hip/hip_runtime.h>
#include <math.h>

#define NB 1024
#define NC 63
#define NF 250
#define NH 4
#define ND 250
#define NHD 1000

typedef __bf16 bf16x8 __attribute__((ext_vector_type(8)));
typedef float f32x4 __attribute__((ext_vector_type(4)));

// ============================================================================
// k_fused (R12-exact): one batch per block, 64KB LDS, VGPR ~104, 2 blocks/CU.
// R17 lesson: adding the hp branch pushed VGPR to 136 -> waves/CU halved
// (m69 cliff at 128) -> 96us. Keep this kernel's register profile clean.
// ============================================================================
__global__ __launch_bounds__(256) void k_fused(const float* __restrict__ x,
                                               const __bf16* __restrict__ WcT,
                                               const float* __restrict__ biasc,
                                               float* __restrict__ out,
                                               float* __restrict__ partial) {
    __shared__ __align__(16) __bf16 Xh[64 * 256];   // 32 KB (rows 0-1 overlay moments post-compute)
    __shared__ __align__(16) __bf16 Xl[64 * 256];   // 32 KB
    float* const momS = (float*)Xh;
    const int t = threadIdx.x;
    const int w = t >> 6, l = t & 63;
    const int l16 = l & 15, lq = l >> 4;
    const int swz = (l16 & 7) << 3;
    const int nb = w * 64;

    {
        const int kz = t ^ 56;                 // (63&7)<<3
        Xh[63 * 256 + kz] = (__bf16)1.0f;
        Xl[63 * 256 + kz] = (__bf16)0.0f;
    }

    float bc[4];
#pragma unroll
    for (int ni = 0; ni < 4; ++ni) {
        const int col = nb + ni * 16 + l16;
        bc[ni] = (col < ND) ? biasc[col] : 0.f;
    }

    const f32x4 z4 = {0.f, 0.f, 0.f, 0.f};
    const int b = blockIdx.x;
    const float* xb = x + (size_t)b * (NC * NF);

    // ---- stage: 63 rows x 32 octets, coalesced float2 -> hi/lo bf16
#pragma unroll
    for (int it = 0; it < 8; ++it) {
        const int u = it * 256 + t;
        if (u < 2016) {
            const int row = u >> 5;
            const int ko = (u & 31) << 3;
            const float* src = xb + row * NF + ko;
            float v[8];
#pragma unroll
            for (int q = 0; q < 4; ++q) {
                if (ko + q * 2 < NF) {
                    const float2 p = *(const float2*)(src + q * 2);
                    v[2 * q] = p.x; v[2 * q + 1] = p.y;
                } else { v[2 * q] = 0.f; v[2 * q + 1] = 0.f; }
            }
            bf16x8 h, lo_;
#pragma unroll
            for (int j = 0; j < 8; ++j) {
                h[j] = (__bf16)v[j];
                lo_[j] = (__bf16)(v[j] - (float)h[j]);
            }
            const int kS = ko ^ ((row & 7) << 3);
            *(bf16x8*)&Xh[row * 256 + kS] = h;
            *(bf16x8*)&Xl[row * 256 + kS] = lo_;
        }
    }
    __syncthreads();   // staging complete

    bf16x8 bfr[4][4];
    f32x4 accM[4][4];
    f32x4 accG[4];
#pragma unroll
    for (int mi = 0; mi < 4; ++mi)
#pragma unroll
        for (int ni = 0; ni < 4; ++ni) accM[mi][ni] = z4;
#pragma unroll
    for (int ni = 0; ni < 4; ++ni) accG[ni] = z4;

    const int garow = (16 * w + l16) * 256;   // gram A row base

    // ================= K half 0 (kc 0..3) =================
#pragma unroll
    for (int ni = 0; ni < 4; ++ni) {
        const int n = nb + ni * 16 + l16;
#pragma unroll
        for (int kk = 0; kk < 4; ++kk)
            bfr[ni][kk] = *(const bf16x8*)(WcT + (size_t)n * 256 + kk * 32 + lq * 8);
    }
#pragma unroll
    for (int kk = 0; kk < 4; ++kk) {
        const int kb = (kk * 32 + lq * 8) ^ swz;
        bf16x8 hi[4], lo[4];
#pragma unroll
        for (int r = 0; r < 4; ++r) {
            hi[r] = *(const bf16x8*)&Xh[(r * 16 + l16) * 256 + kb];
            lo[r] = *(const bf16x8*)&Xl[(r * 16 + l16) * 256 + kb];
        }
        const bf16x8 ah = *(const bf16x8*)&Xh[garow + kb];
        const bf16x8 al = *(const bf16x8*)&Xl[garow + kb];
#pragma unroll
        for (int mi = 0; mi < 4; ++mi)
#pragma unroll
            for (int ni = 0; ni < 4; ++ni)
                accM[mi][ni] = __builtin_amdgcn_mfma_f32_16x16x32_bf16(
                    hi[mi], bfr[ni][kk], accM[mi][ni], 0, 0, 0);
#pragma unroll
        for (int ni = 0; ni < 4; ++ni) {
            accG[ni] = __builtin_amdgcn_mfma_f32_16x16x32_bf16(ah, hi[ni], accG[ni], 0, 0, 0);
            accG[ni] = __builtin_amdgcn_mfma_f32_16x16x32_bf16(ah, lo[ni], accG[ni], 0, 0, 0);
            accG[ni] = __builtin_amdgcn_mfma_f32_16x16x32_bf16(al, hi[ni], accG[ni], 0, 0, 0);
        }
    }

    // ================= K half 1 (kc 4..7) =================
#pragma unroll
    for (int ni = 0; ni < 4; ++ni) {
        const int n = nb + ni * 16 + l16;
#pragma unroll
        for (int kk = 0; kk < 4; ++kk)
            bfr[ni][kk] = *(const bf16x8*)(WcT + (size_t)n * 256 + (4 + kk) * 32 + lq * 8);
    }
#pragma unroll
    for (int kk = 0; kk < 4; ++kk) {
        const int kb = ((4 + kk) * 32 + lq * 8) ^ swz;
        bf16x8 hi[4], lo[4];
#pragma unroll
        for (int r = 0; r < 4; ++r) {
            hi[r] = *(const bf16x8*)&Xh[(r * 16 + l16) * 256 + kb];
            lo[r] = *(const bf16x8*)&Xl[(r * 16 + l16) * 256 + kb];
        }
        const bf16x8 ah = *(const bf16x8*)&Xh[garow + kb];
        const bf16x8 al = *(const bf16x8*)&Xl[garow + kb];
#pragma unroll
        for (int mi = 0; mi < 4; ++mi)
#pragma unroll
            for (int ni = 0; ni < 4; ++ni)
                accM[mi][ni] = __builtin_amdgcn_mfma_f32_16x16x32_bf16(
                    hi[mi], bfr[ni][kk], accM[mi][ni], 0, 0, 0);
#pragma unroll
        for (int ni = 0; ni < 4; ++ni) {
            accG[ni] = __builtin_amdgcn_mfma_f32_16x16x32_bf16(ah, hi[ni], accG[ni], 0, 0, 0);
            accG[ni] = __builtin_amdgcn_mfma_f32_16x16x32_bf16(ah, lo[ni], accG[ni], 0, 0, 0);
            accG[ni] = __builtin_amdgcn_mfma_f32_16x16x32_bf16(al, hi[ni], accG[ni], 0, 0, 0);
        }
    }

    __syncthreads();   // ALL plane reads done before overlay write (alias hazard)

    if (l16 == 15) {
#pragma unroll
        for (int r = 0; r < 4; ++r) momS[16 * w + lq * 4 + r] = accG[3][r];
    }
    if ((l16 >> 2) == lq) momS[64 + 16 * w + l16] = accG[w][l16 & 3];
    __syncthreads();
    if (t < 64) {
        const float S = momS[t], SSv = momS[64 + t];
        float m = S * (1.f / (float)NF);
        const float var = (SSv - S * S * (1.f / (float)NF)) * (1.f / (float)(NF - 1));
        float sc = 1.f / (sqrtf(var) + 1e-8f);
        if (t >= NC) { m = 0.f; sc = 0.f; }
        momS[128 + t] = m; momS[192 + t] = sc;
    }
    __syncthreads();

    float mr[4], sr[4];
#pragma unroll
    for (int r = 0; r < 4; ++r) {
        const int row = 16 * w + lq * 4 + r;
        mr[r] = momS[128 + row]; sr[r] = momS[192 + row];
    }
#pragma unroll
    for (int ni = 0; ni < 4; ++ni) {
        const float mc = momS[128 + 16 * ni + l16];
        const float sc = momS[192 + 16 * ni + l16];
#pragma unroll
        for (int r = 0; r < 4; ++r) {
            const int row = 16 * w + lq * 4 + r;
            const int col = 16 * ni + l16;
            partial[(size_t)b * 4096 + row * 64 + col] =
                (accG[ni][r] - (float)NF * mr[r] * mc) * sr[r] * sc;
        }
    }

    const size_t ob = (size_t)b * NC;
#pragma unroll
    for (int mi = 0; mi < 4; ++mi) {
#pragma unroll
        for (int r = 0; r < 4; ++r) {
            const int rt = mi * 16 + lq * 4 + r;
            if (rt < NC) {
#pragma unroll
                for (int ni = 0; ni < 4; ++ni) {
                    const int col = nb + ni * 16 + l16;
                    if (col < ND)
                        out[(ob + rt) * ND + col] = accM[mi][ni][r] + bc[ni];
                }
            }
        }
    }
}

// ============================================================================
// k_gswc = k_wc_part UNION k_gs. (unchanged)
// ============================================================================
__global__ __launch_bounds__(256) void k_gswc(const float* __restrict__ Wg,
                                              const float* __restrict__ att_src,
                                              const float* __restrict__ att_dst,
                                              const float* __restrict__ bias_gat,
                                              const float* __restrict__ Wp,
                                              float* __restrict__ pWcT,
                                              float* __restrict__ pbias,
                                              float* __restrict__ gs,
                                              float* __restrict__ gd) {
    __shared__ float rows[250];
    const int b = blockIdx.x, t = threadIdx.x;
    if (b < 1000) {
        const int fb = (b >> 3) * 2, kq = b & 7;
        if (t < 250)
            rows[t] = Wg[(size_t)(fb + t / 125) * NHD + kq * 125 + (t % 125)];
        __syncthreads();
        if (t < ND) {
            float a0 = 0.f, a1 = 0.f;
            const float* wp = Wp + (size_t)(kq * 125) * ND + t;
            for (int k = 0; k < 125; ++k) {
                float wv = wp[(size_t)k * ND];
                a0 += rows[k] * wv;
                a1 += rows[125 + k] * wv;
            }
            pWcT[(size_t)kq * 65536 + (size_t)t * 256 + fb] = a0;
            pWcT[(size_t)kq * 65536 + (size_t)t * 256 + fb + 1] = a1;
        }
    } else if (b < 1008) {
        const int kq = b - 1000;
        if (t < ND) {
            float acc = 0.f;
            for (int k = kq * 125; k < kq * 125 + 125; ++k)
                acc += bias_gat[k] * Wp[(size_t)k * ND + t];
            pbias[kq * 256 + t] = acc;
        }
    } else {
        const int f = b - 1008;
        const int h = t >> 6, l = t & 63;
        const float* wr = Wg + (size_t)f * NHD + h * ND;
        const float* sp = att_src + h * ND;
        const float* dp = att_dst + h * ND;
        float s = 0.f, d = 0.f;
#pragma unroll
        for (int q = 0; q < 4; ++q) {
            const int dd = l + q * 64;
            if (dd < ND) {
                const float wv = wr[dd];
                s += wv * sp[dd];
                d += wv * dp[dd];
            }
        }
#pragma unroll
        for (int off = 32; off >= 1; off >>= 1) {
            s += __shfl_down(s, off);
            d += __shfl_down(d, off);
        }
        if (l == 0) { gs[f * NH + h] = s; gd[f * NH + h] = d; }
    }
}

// ============================================================================
// k_wct: WcT + per-head WchT bf16 + biasc. grid 257. (unchanged)
// ============================================================================
__global__ __launch_bounds__(256) void k_wct(const float* __restrict__ pWcT,
                                             const float* __restrict__ pbias,
                                             const float* __restrict__ b_proj,
                                             __bf16* __restrict__ WcT,
                                             __bf16* __restrict__ WchT,
                                             float* __restrict__ biasc) {
    const int n = blockIdx.x, t = threadIdx.x;
    if (n < 256) {
        float v[8];
        float tot = 0.f;
#pragma unroll
        for (int kq = 0; kq < 8; ++kq) {
            float xv = 0.f;
            if (n < ND && t < NF) xv = pWcT[(size_t)kq * 65536 + (size_t)n * 256 + t];
            v[kq] = xv; tot += xv;
        }
        WcT[n * 256 + t] = (__bf16)tot;
#pragma unroll
        for (int h = 0; h < NH; ++h)
            WchT[h * 65536 + n * 256 + t] = (__bf16)(v[2 * h] + v[2 * h + 1]);
    } else {
        if (t < ND) {
            float v = 0.f;
#pragma unroll
            for (int kq = 0; kq < 8; ++kq) v += pbias[kq * 256 + t];
            biasc[t] = v + b_proj[t];
        }
    }
}

// ============================================================================
// k_adjred_asad_hp: blocks 0..62 adj-reduce; 63 asad; 64..67 hp (head b-64).
// hp lives here because <=68 blocks -> occupancy/VGPR irrelevant (R17 lesson:
// hp's 128-VGPR bfr array must NOT share a kernel with the 1024-block GEMM).
// grid 68 x 512.
// ============================================================================
__global__ __launch_bounds__(512) void k_adjred_asad_hp(const float* __restrict__ partial,
                                                        const float* __restrict__ x,
                                                        const float* __restrict__ gs,
                                                        const float* __restrict__ gd,
                                                        const __bf16* __restrict__ WchT,
                                                        float* __restrict__ adj,
                                                        float* __restrict__ as_,
                                                        float* __restrict__ ad_,
                                                        float* __restrict__ hp) {
    __shared__ __align__(16) float smem[NC * NF + 2 * NHD];   // 71 KB union
    const int t = threadIdx.x;
    if (blockIdx.x < 63) {
        float (*red)[64] = (float(*)[64])smem;
        const int row = blockIdx.x;
        const int c = t & 63, g = t >> 6;
        float s = 0.f;
        const float* p = partial + (size_t)(g * 128) * 4096 + row * 64 + c;
#pragma unroll 8
        for (int i = 0; i < 128; ++i) s += p[(size_t)i * 4096];
        red[g][c] = s;
        __syncthreads();
        if (t < NC) {
            float tot = 0.f;
#pragma unroll
            for (int gg = 0; gg < 8; ++gg) tot += red[gg][t];
            adj[row * NC + t] = tot * (1.f / ((float)NF * (float)NB));
        }
    } else if (blockIdx.x == 63) {
        float* x0S = smem;                      // 15750
        float* gsS = smem + NC * NF;            // 1000
        float* gdS = gsS + NHD;                 // 1000
        for (int e = t; e < NC * NF; e += 512) x0S[e] = x[e];
        for (int e = t; e < NF * NH; e += 512) { gsS[e] = gs[e]; gdS[e] = gd[e]; }
        __syncthreads();
        if (t < NC * NH) {
            const int c = t >> 2, h = t & 3;
            float s = 0.f, d = 0.f;
#pragma unroll 5
            for (int f = 0; f < NF; ++f) {
                const float xv = x0S[c * NF + f];
                s += xv * gsS[f * NH + h];
                d += xv * gdS[f * NH + h];
            }
            as_[t] = s; ad_[t] = d;
        }
    } else {
        // ---- hp: head h = blockIdx.x - 64. Stage x0 with all 512 threads.
        __bf16* Xs = (__bf16*)smem;             // 32 KB
        const int h = blockIdx.x - 64;
#pragma unroll
        for (int it = 0; it < 4; ++it) {
            const int u = it * 512 + t;         // 0..2047
            const int row = u >> 5;
            const int ko = (u & 31) << 3;
            float v[8];
#pragma unroll
            for (int q = 0; q < 4; ++q) { v[2 * q] = 0.f; v[2 * q + 1] = 0.f; }
            if (row < NC) {
                const float* src = x + row * NF + ko;
#pragma unroll
                for (int q = 0; q < 4; ++q) {
                    if (ko + 2 * q + 1 < NF) {
                        const float2 p = *(const float2*)(src + 2 * q);
                        v[2 * q] = p.x; v[2 * q + 1] = p.y;
                    }
                }
            }
            bf16x8 hv;
#pragma unroll
            for (int jj = 0; jj < 8; ++jj) hv[jj] = (__bf16)v[jj];
            *(bf16x8*)&Xs[row * 256 + (ko ^ ((row & 7) << 3))] = hv;
        }
        __syncthreads();

        if (t < 256) {
            const int w = t >> 6, l = t & 63;
            const int l16 = l & 15, lq = l >> 4;
            const int nb = w * 64;
            const int swz = (l16 & 7) << 3;
            const __bf16* Wh = WchT + h * 65536;
            bf16x8 bfr[4][8];
#pragma unroll
            for (int ni = 0; ni < 4; ++ni) {
                const int n = nb + ni * 16 + l16;
#pragma unroll
                for (int kc = 0; kc < 8; ++kc)
                    bfr[ni][kc] = *(const bf16x8*)(Wh + (size_t)n * 256 + kc * 32 + lq * 8);
            }
            f32x4 acc[4][4];
            const f32x4 z4 = {0.f, 0.f, 0.f, 0.f};
#pragma unroll
            for (int mi = 0; mi < 4; ++mi)
#pragma unroll
                for (int ni = 0; ni < 4; ++ni) acc[mi][ni] = z4;
#pragma unroll
            for (int kc = 0; kc < 8; ++kc) {
                const int kb = (kc * 32 + lq * 8) ^ swz;
                bf16x8 afr[4];
#pragma unroll
                for (int mi = 0; mi < 4; ++mi)
                    afr[mi] = *(const bf16x8*)&Xs[(mi * 16 + l16) * 256 + kb];
#pragma unroll
                for (int mi = 0; mi < 4; ++mi)
#pragma unroll
                    for (int ni = 0; ni < 4; ++ni)
                        acc[mi][ni] = __builtin_amdgcn_mfma_f32_16x16x32_bf16(
                            afr[mi], bfr[ni][kc], acc[mi][ni], 0, 0, 0);
            }
#pragma unroll
            for (int mi = 0; mi < 4; ++mi)
#pragma unroll
                for (int r = 0; r < 4; ++r) {
                    const int row = mi * 16 + lq * 4 + r;
#pragma unroll
                    for (int ni = 0; ni < 4; ++ni) {
                        const int col = nb + ni * 16 + l16;
                        hp[(size_t)(h * 64 + row) * 256 + col] = acc[mi][ni][r];
                    }
                }
        }
    }
}

// ============================================================================
// k_out0: register softmax + projection over hp (K=256). (unchanged)
// ============================================================================
__global__ __launch_bounds__(512) void k_out0(const float* __restrict__ adj,
                                              const float* __restrict__ as_,
                                              const float* __restrict__ ad_,
                                              const float* __restrict__ hp,
                                              const float* __restrict__ biasc,
                                              float* __restrict__ out) {
    __shared__ float adjS[NC * NC];
    __shared__ float thS[NC];
    __shared__ float asS[NC * 5];        // stride-5 pad
    __shared__ float adS[NC * NH];
    __shared__ float wS[256];            // w[h*64+i], zeros at i=63
    __shared__ float psum[2][256];
    const int j = blockIdx.x, t = threadIdx.x;
    const int w = t >> 6, l = t & 63;

    for (int e = t; e < NC * NC; e += 512) adjS[e] = adj[e];
    if (t < NC * NH) { asS[(t >> 2) * 5 + (t & 3)] = as_[t]; adS[t] = ad_[t]; }
    __syncthreads();

    for (int r = w; r < NC; r += 8) {
        const float v = (l < NC) ? adjS[r * NC + l] : -INFINITY;
        float prev = INFINITY;
        int krem = 8;                     // TOP_K
        float th = -INFINITY;
#pragma unroll
        for (int iter = 0; iter < 8; ++iter) {
            const float vm = (v < prev) ? v : -INFINITY;
            float m = vm;
#pragma unroll
            for (int off = 32; off >= 1; off >>= 1) m = fmaxf(m, __shfl_xor(m, off));
            const unsigned long long bl = __ballot(vm == m);
            const int cnt = __popcll(bl);
            if (cnt >= krem) { th = m; break; }
            krem -= cnt; prev = m;
        }
        if (l == 0) thS[r] = th;
    }
    __syncthreads();

    if (w < NH) {
        const int h = w, i = l;
        const float adv = adS[j * NH + h];
        const float a = (i < NC) ? adjS[i * NC + j] : 0.f;
        const bool msk = (i < NC) && ((i == j) || ((a >= thS[i]) && (a != 0.f)));
        float e = 0.f;
        if (msk) { e = asS[i * 5 + h] + adv; e = e > 0.f ? e : 0.2f * e; }
        float m = msk ? e : -INFINITY;
#pragma unroll
        for (int off = 32; off >= 1; off >>= 1) m = fmaxf(m, __shfl_xor(m, off));
        const float p = msk ? __expf(e - m) : 0.f;
        float s = p;
#pragma unroll
        for (int off = 32; off >= 1; off >>= 1) s += __shfl_xor(s, off);
        wS[(h << 6) + l] = p / s;        // 0 for i=63 / unmasked
    }
    __syncthreads();

    const int q = t >> 8, col = t & 255;
    float acc = 0.f;
    const float* hpc = hp + col;
#pragma unroll 8
    for (int e = q * 128; e < q * 128 + 128; ++e)
        acc += wS[e] * hpc[(size_t)e * 256];
    psum[q][col] = acc;
    __syncthreads();
    if (t < ND) out[(size_t)j * ND + t] = psum[0][t] + psum[1][t] + biasc[t];
}

// ============================================================================
extern "C" void kernel_launch(void* const* d_in, const int* in_sizes, int n_in,
                              void* d_out, int out_size, void* d_ws, size_t ws_size,
                              hipStream_t stream) {
    const float* x       = (const float*)d_in[0];
    const float* Wg      = (const float*)d_in[1];
    const float* att_src = (const float*)d_in[2];
    const float* att_dst = (const float*)d_in[3];
    const float* bias_g  = (const float*)d_in[4];
    const float* Wp      = (const float*)d_in[5];
    const float* b_proj  = (const float*)d_in[6];
    float* out = (float*)d_out;
    float* ws  = (float*)d_ws;

    __bf16* WcT    = (__bf16*)ws;                 // 65536 bf16  = 32768 f
    __bf16* WchT   = (__bf16*)(ws + 32768);       // 4*65536 bf16 = 131072 f
    float* pWcT    = ws + 32768 + 131072;         // 8*65536 = 524288
    float* pbias   = pWcT + 8 * 65536;            // 2048
    float* biasc   = pbias + 2048;                // 256
    float* partial = biasc + 256;                 // 1024*4096 = 4,194,304
    float* adj     = partial + 1024 * 4096;       // 3969
    float* hp      = adj + NC * NC;               // 256*256 = 65536
    float* gs      = hp + 65536;                  // 1000
    float* gd      = gs + 1000;                   // 1000
    float* as_     = gd + 1000;                   // 252
    float* ad_     = as_ + 252;                   // 252  (total ~19.7 MB)

    k_gswc<<<1258, 256, 0, stream>>>(Wg, att_src, att_dst, bias_g, Wp,
                                     pWcT, pbias, gs, gd);
    k_wct<<<257, 256, 0, stream>>>(pWcT, pbias, b_proj, WcT, WchT, biasc);
    k_fused<<<1024, 256, 0, stream>>>(x, WcT, biasc, out, partial);
    k_adjred_asad_hp<<<68, 512, 0, stream>>>(partial, x, gs, gd, WchT,
                                             adj, as_, ad_, hp);
    k_out0<<<63, 512, 0, stream>>>(adj, as_, ad_, hp, biasc, out);
}

// Round 19
// 100.227 us; speedup vs baseline: 3.8875x; 1.0039x over previous
//
#include <hip/hip_runtime.h>
#include <math.h>

#define NB 1024
#define NC 63
#define NF 250
#define NH 4
#define ND 250
#define NHD 1000

typedef __bf16 bf16x8 __attribute__((ext_vector_type(8)));
typedef float f32x4 __attribute__((ext_vector_type(4)));

// ============================================================================
// k_fused v7: one batch per block, K-SPLIT staging (32KB LDS), DEFAULT bounds.
// R13/R14 failed because the explicit 2nd launch_bounds arg capped VGPR below
// the ~150 live regs -> spill (R13 VGPR=64, R14 VGPR=84 + inflated FETCH/
// WRITE). Structure itself is correctness-proven. With plain (256) the
// allocator picks spill-free (~104-130 VGPR) -> 32KB LDS gives ~4 blocks/CU
// (16 waves) vs R18's 2 blocks -> stage latency finally hidden.
// ============================================================================
__global__ __launch_bounds__(256) void k_fused(const float* __restrict__ x,
                                               const __bf16* __restrict__ WcT,
                                               const float* __restrict__ biasc,
                                               float* __restrict__ out,
                                               float* __restrict__ partial) {
    __shared__ __align__(16) __bf16 Xh[64 * 128];   // 16 KB (rows 0-1 overlay moments post-compute)
    __shared__ __align__(16) __bf16 Xl[64 * 128];   // 16 KB
    float* const momS = (float*)Xh;  // [0:64)=S [64:128)=SS [128:192)=mean [192:256)=scl
    const int t = threadIdx.x;
    const int w = t >> 6, l = t & 63;
    const int l16 = l & 15, lq = l >> 4;
    const int swz = (l16 & 7) << 3;
    const int nb = w * 64;

    float bc[4];
#pragma unroll
    for (int ni = 0; ni < 4; ++ni) {
        const int col = nb + ni * 16 + l16;
        bc[ni] = (col < ND) ? biasc[col] : 0.f;
    }

    const f32x4 z4 = {0.f, 0.f, 0.f, 0.f};
    const int b = blockIdx.x;
    const float* xb = x + (size_t)b * (NC * NF);
    const int garow = (16 * w + l16) * 128;   // gram A row base (half-K buffer)

    bf16x8 bfr[4][4];
    f32x4 accM[4][4];
    f32x4 accG[4];
#pragma unroll
    for (int mi = 0; mi < 4; ++mi)
#pragma unroll
        for (int ni = 0; ni < 4; ++ni) accM[mi][ni] = z4;
#pragma unroll
    for (int ni = 0; ni < 4; ++ni) accG[ni] = z4;

#pragma unroll
    for (int h = 0; h < 2; ++h) {
        if (h) __syncthreads();   // protect buffer from previous half's readers

        // ---- stage half h: 63 rows x 16 octets (1008 units), coalesced
#pragma unroll
        for (int it = 0; it < 4; ++it) {
            const int u = it * 256 + t;
            if (u < 1008) {
                const int row = u >> 4;
                const int ko = (u & 15) << 3;          // element within half
                const int kg = h * 128 + ko;           // global k
                const float* src = xb + row * NF + kg;
                float v[8];
#pragma unroll
                for (int q = 0; q < 4; ++q) {
                    if (kg + q * 2 + 1 < NF) {
                        const float2 p = *(const float2*)(src + q * 2);
                        v[2 * q] = p.x; v[2 * q + 1] = p.y;
                    } else { v[2 * q] = 0.f; v[2 * q + 1] = 0.f; }
                }
                bf16x8 hv, lo_;
#pragma unroll
                for (int j = 0; j < 8; ++j) {
                    hv[j] = (__bf16)v[j];
                    lo_[j] = (__bf16)(v[j] - (float)hv[j]);
                }
                const int kS = ko ^ ((row & 7) << 3);
                *(bf16x8*)&Xh[row * 128 + kS] = hv;
                *(bf16x8*)&Xl[row * 128 + kS] = lo_;
            }
        }
        // ---- ones row (row 63): logical element e = h*128+t, swizzled t^56
        if (t < 128) {
            const int kz = t ^ 56;                     // (63&7)<<3
            Xh[63 * 128 + kz] = (h * 128 + t < NF) ? (__bf16)1.0f : (__bf16)0.0f;
            Xl[63 * 128 + kz] = (__bf16)0.0f;
        }
        __syncthreads();   // staging complete

        // ---- B fragments for this half (L2-resident WcT)
#pragma unroll
        for (int ni = 0; ni < 4; ++ni) {
            const int n = nb + ni * 16 + l16;
#pragma unroll
            for (int kk = 0; kk < 4; ++kk)
                bfr[ni][kk] = *(const bf16x8*)(WcT + (size_t)n * 256 + (h * 4 + kk) * 32 + lq * 8);
        }

        // ---- main + gram MFMA over this half's 4 K-chunks
#pragma unroll
        for (int kk = 0; kk < 4; ++kk) {
            const int kb = (kk * 32 + lq * 8) ^ swz;
            bf16x8 hi[4], lo[4];
#pragma unroll
            for (int r = 0; r < 4; ++r) {
                hi[r] = *(const bf16x8*)&Xh[(r * 16 + l16) * 128 + kb];
                lo[r] = *(const bf16x8*)&Xl[(r * 16 + l16) * 128 + kb];
            }
            const bf16x8 ah = *(const bf16x8*)&Xh[garow + kb];
            const bf16x8 al = *(const bf16x8*)&Xl[garow + kb];
#pragma unroll
            for (int mi = 0; mi < 4; ++mi)
#pragma unroll
                for (int ni = 0; ni < 4; ++ni)
                    accM[mi][ni] = __builtin_amdgcn_mfma_f32_16x16x32_bf16(
                        hi[mi], bfr[ni][kk], accM[mi][ni], 0, 0, 0);
#pragma unroll
            for (int ni = 0; ni < 4; ++ni) {
                accG[ni] = __builtin_amdgcn_mfma_f32_16x16x32_bf16(ah, hi[ni], accG[ni], 0, 0, 0);
                accG[ni] = __builtin_amdgcn_mfma_f32_16x16x32_bf16(ah, lo[ni], accG[ni], 0, 0, 0);
                accG[ni] = __builtin_amdgcn_mfma_f32_16x16x32_bf16(al, hi[ni], accG[ni], 0, 0, 0);
            }
        }
    }

    __syncthreads();   // ALL plane reads done before overlay write (alias hazard)

    // ---- moments into overlay: col 63 (S) from tile ni=3; diag (SS)
    if (l16 == 15) {
#pragma unroll
        for (int r = 0; r < 4; ++r) momS[16 * w + lq * 4 + r] = accG[3][r];
    }
    if ((l16 >> 2) == lq) momS[64 + 16 * w + l16] = accG[w][l16 & 3];
    __syncthreads();
    if (t < 64) {
        const float S = momS[t], SSv = momS[64 + t];
        float m = S * (1.f / (float)NF);
        const float var = (SSv - S * S * (1.f / (float)NF)) * (1.f / (float)(NF - 1));
        float sc = 1.f / (sqrtf(var) + 1e-8f);
        if (t >= NC) { m = 0.f; sc = 0.f; }
        momS[128 + t] = m; momS[192 + t] = sc;
    }
    __syncthreads();

    // ---- gram fixup -> partial (direct)
    float mr[4], sr[4];
#pragma unroll
    for (int r = 0; r < 4; ++r) {
        const int row = 16 * w + lq * 4 + r;
        mr[r] = momS[128 + row]; sr[r] = momS[192 + row];
    }
#pragma unroll
    for (int ni = 0; ni < 4; ++ni) {
        const float mc = momS[128 + 16 * ni + l16];
        const float sc = momS[192 + 16 * ni + l16];
#pragma unroll
        for (int r = 0; r < 4; ++r) {
            const int row = 16 * w + lq * 4 + r;
            const int col = 16 * ni + l16;
            partial[(size_t)b * 4096 + row * 64 + col] =
                (accG[ni][r] - (float)NF * mr[r] * mc) * sr[r] * sc;
        }
    }

    // ---- main stores: rows 0..62 of this batch
    const size_t ob = (size_t)b * NC;
#pragma unroll
    for (int mi = 0; mi < 4; ++mi) {
#pragma unroll
        for (int r = 0; r < 4; ++r) {
            const int rt = mi * 16 + lq * 4 + r;
            if (rt < NC) {
#pragma unroll
                for (int ni = 0; ni < 4; ++ni) {
                    const int col = nb + ni * 16 + l16;
                    if (col < ND)
                        out[(ob + rt) * ND + col] = accM[mi][ni][r] + bc[ni];
                }
            }
        }
    }
}

// ============================================================================
// k_gswc = k_wc_part UNION k_gs. (unchanged)
// ============================================================================
__global__ __launch_bounds__(256) void k_gswc(const float* __restrict__ Wg,
                                              const float* __restrict__ att_src,
                                              const float* __restrict__ att_dst,
                                              const float* __restrict__ bias_gat,
                                              const float* __restrict__ Wp,
                                              float* __restrict__ pWcT,
                                              float* __restrict__ pbias,
                                              float* __restrict__ gs,
                                              float* __restrict__ gd) {
    __shared__ float rows[250];
    const int b = blockIdx.x, t = threadIdx.x;
    if (b < 1000) {
        const int fb = (b >> 3) * 2, kq = b & 7;
        if (t < 250)
            rows[t] = Wg[(size_t)(fb + t / 125) * NHD + kq * 125 + (t % 125)];
        __syncthreads();
        if (t < ND) {
            float a0 = 0.f, a1 = 0.f;
            const float* wp = Wp + (size_t)(kq * 125) * ND + t;
            for (int k = 0; k < 125; ++k) {
                float wv = wp[(size_t)k * ND];
                a0 += rows[k] * wv;
                a1 += rows[125 + k] * wv;
            }
            pWcT[(size_t)kq * 65536 + (size_t)t * 256 + fb] = a0;
            pWcT[(size_t)kq * 65536 + (size_t)t * 256 + fb + 1] = a1;
        }
    } else if (b < 1008) {
        const int kq = b - 1000;
        if (t < ND) {
            float acc = 0.f;
            for (int k = kq * 125; k < kq * 125 + 125; ++k)
                acc += bias_gat[k] * Wp[(size_t)k * ND + t];
            pbias[kq * 256 + t] = acc;
        }
    } else {
        const int f = b - 1008;
        const int h = t >> 6, l = t & 63;
        const float* wr = Wg + (size_t)f * NHD + h * ND;
        const float* sp = att_src + h * ND;
        const float* dp = att_dst + h * ND;
        float s = 0.f, d = 0.f;
#pragma unroll
        for (int q = 0; q < 4; ++q) {
            const int dd = l + q * 64;
            if (dd < ND) {
                const float wv = wr[dd];
                s += wv * sp[dd];
                d += wv * dp[dd];
            }
        }
#pragma unroll
        for (int off = 32; off >= 1; off >>= 1) {
            s += __shfl_down(s, off);
            d += __shfl_down(d, off);
        }
        if (l == 0) { gs[f * NH + h] = s; gd[f * NH + h] = d; }
    }
}

// ============================================================================
// k_wct: WcT + per-head WchT bf16 + biasc. grid 257. (unchanged)
// ============================================================================
__global__ __launch_bounds__(256) void k_wct(const float* __restrict__ pWcT,
                                             const float* __restrict__ pbias,
                                             const float* __restrict__ b_proj,
                                             __bf16* __restrict__ WcT,
                                             __bf16* __restrict__ WchT,
                                             float* __restrict__ biasc) {
    const int n = blockIdx.x, t = threadIdx.x;
    if (n < 256) {
        float v[8];
        float tot = 0.f;
#pragma unroll
        for (int kq = 0; kq < 8; ++kq) {
            float xv = 0.f;
            if (n < ND && t < NF) xv = pWcT[(size_t)kq * 65536 + (size_t)n * 256 + t];
            v[kq] = xv; tot += xv;
        }
        WcT[n * 256 + t] = (__bf16)tot;
#pragma unroll
        for (int h = 0; h < NH; ++h)
            WchT[h * 65536 + n * 256 + t] = (__bf16)(v[2 * h] + v[2 * h + 1]);
    } else {
        if (t < ND) {
            float v = 0.f;
#pragma unroll
            for (int kq = 0; kq < 8; ++kq) v += pbias[kq * 256 + t];
            biasc[t] = v + b_proj[t];
        }
    }
}

// ============================================================================
// k_adjred_asad_hp: blocks 0..62 adj-reduce; 63 asad; 64..67 hp. (unchanged)
// ============================================================================
__global__ __launch_bounds__(512) void k_adjred_asad_hp(const float* __restrict__ partial,
                                                        const float* __restrict__ x,
                                                        const float* __restrict__ gs,
                                                        const float* __restrict__ gd,
                                                        const __bf16* __restrict__ WchT,
                                                        float* __restrict__ adj,
                                                        float* __restrict__ as_,
                                                        float* __restrict__ ad_,
                                                        float* __restrict__ hp) {
    __shared__ __align__(16) float smem[NC * NF + 2 * NHD];   // 71 KB union
    const int t = threadIdx.x;
    if (blockIdx.x < 63) {
        float (*red)[64] = (float(*)[64])smem;
        const int row = blockIdx.x;
        const int c = t & 63, g = t >> 6;
        float s = 0.f;
        const float* p = partial + (size_t)(g * 128) * 4096 + row * 64 + c;
#pragma unroll 8
        for (int i = 0; i < 128; ++i) s += p[(size_t)i * 4096];
        red[g][c] = s;
        __syncthreads();
        if (t < NC) {
            float tot = 0.f;
#pragma unroll
            for (int gg = 0; gg < 8; ++gg) tot += red[gg][t];
            adj[row * NC + t] = tot * (1.f / ((float)NF * (float)NB));
        }
    } else if (blockIdx.x == 63) {
        float* x0S = smem;                      // 15750
        float* gsS = smem + NC * NF;            // 1000
        float* gdS = gsS + NHD;                 // 1000
        for (int e = t; e < NC * NF; e += 512) x0S[e] = x[e];
        for (int e = t; e < NF * NH; e += 512) { gsS[e] = gs[e]; gdS[e] = gd[e]; }
        __syncthreads();
        if (t < NC * NH) {
            const int c = t >> 2, h = t & 3;
            float s = 0.f, d = 0.f;
#pragma unroll 5
            for (int f = 0; f < NF; ++f) {
                const float xv = x0S[c * NF + f];
                s += xv * gsS[f * NH + h];
                d += xv * gdS[f * NH + h];
            }
            as_[t] = s; ad_[t] = d;
        }
    } else {
        // ---- hp: head h = blockIdx.x - 64. Stage x0 with all 512 threads.
        __bf16* Xs = (__bf16*)smem;             // 32 KB
        const int h = blockIdx.x - 64;
#pragma unroll
        for (int it = 0; it < 4; ++it) {
            const int u = it * 512 + t;         // 0..2047
            const int row = u >> 5;
            const int ko = (u & 31) << 3;
            float v[8];
#pragma unroll
            for (int q = 0; q < 4; ++q) { v[2 * q] = 0.f; v[2 * q + 1] = 0.f; }
            if (row < NC) {
                const float* src = x + row * NF + ko;
#pragma unroll
                for (int q = 0; q < 4; ++q) {
                    if (ko + 2 * q + 1 < NF) {
                        const float2 p = *(const float2*)(src + 2 * q);
                        v[2 * q] = p.x; v[2 * q + 1] = p.y;
                    }
                }
            }
            bf16x8 hv;
#pragma unroll
            for (int jj = 0; jj < 8; ++jj) hv[jj] = (__bf16)v[jj];
            *(bf16x8*)&Xs[row * 256 + (ko ^ ((row & 7) << 3))] = hv;
        }
        __syncthreads();

        if (t < 256) {
            const int w = t >> 6, l = t & 63;
            const int l16 = l & 15, lq = l >> 4;
            const int nb = w * 64;
            const int swz = (l16 & 7) << 3;
            const __bf16* Wh = WchT + h * 65536;
            bf16x8 bfr[4][8];
#pragma unroll
            for (int ni = 0; ni < 4; ++ni) {
                const int n = nb + ni * 16 + l16;
#pragma unroll
                for (int kc = 0; kc < 8; ++kc)
                    bfr[ni][kc] = *(const bf16x8*)(Wh + (size_t)n * 256 + kc * 32 + lq * 8);
            }
            f32x4 acc[4][4];
            const f32x4 z4 = {0.f, 0.f, 0.f, 0.f};
#pragma unroll
            for (int mi = 0; mi < 4; ++mi)
#pragma unroll
                for (int ni = 0; ni < 4; ++ni) acc[mi][ni] = z4;
#pragma unroll
            for (int kc = 0; kc < 8; ++kc) {
                const int kb = (kc * 32 + lq * 8) ^ swz;
                bf16x8 afr[4];
#pragma unroll
                for (int mi = 0; mi < 4; ++mi)
                    afr[mi] = *(const bf16x8*)&Xs[(mi * 16 + l16) * 256 + kb];
#pragma unroll
                for (int mi = 0; mi < 4; ++mi)
#pragma unroll
                    for (int ni = 0; ni < 4; ++ni)
                        acc[mi][ni] = __builtin_amdgcn_mfma_f32_16x16x32_bf16(
                            afr[mi], bfr[ni][kc], acc[mi][ni], 0, 0, 0);
            }
#pragma unroll
            for (int mi = 0; mi < 4; ++mi)
#pragma unroll
                for (int r = 0; r < 4; ++r) {
                    const int row = mi * 16 + lq * 4 + r;
#pragma unroll
                    for (int ni = 0; ni < 4; ++ni) {
                        const int col = nb + ni * 16 + l16;
                        hp[(size_t)(h * 64 + row) * 256 + col] = acc[mi][ni][r];
                    }
                }
        }
    }
}

// ============================================================================
// k_out0: register softmax + projection over hp (K=256). (unchanged)
// ============================================================================
__global__ __launch_bounds__(512) void k_out0(const float* __restrict__ adj,
                                              const float* __restrict__ as_,
                                              const float* __restrict__ ad_,
                                              const float* __restrict__ hp,
                                              const float* __restrict__ biasc,
                                              float* __restrict__ out) {
    __shared__ float adjS[NC * NC];
    __shared__ float thS[NC];
    __shared__ float asS[NC * 5];        // stride-5 pad
    __shared__ float adS[NC * NH];
    __shared__ float wS[256];            // w[h*64+i], zeros at i=63
    __shared__ float psum[2][256];
    const int j = blockIdx.x, t = threadIdx.x;
    const int w = t >> 6, l = t & 63;

    for (int e = t; e < NC * NC; e += 512) adjS[e] = adj[e];
    if (t < NC * NH) { asS[(t >> 2) * 5 + (t & 3)] = as_[t]; adS[t] = ad_[t]; }
    __syncthreads();

    for (int r = w; r < NC; r += 8) {
        const float v = (l < NC) ? adjS[r * NC + l] : -INFINITY;
        float prev = INFINITY;
        int krem = 8;                     // TOP_K
        float th = -INFINITY;
#pragma unroll
        for (int iter = 0; iter < 8; ++iter) {
            const float vm = (v < prev) ? v : -INFINITY;
            float m = vm;
#pragma unroll
            for (int off = 32; off >= 1; off >>= 1) m = fmaxf(m, __shfl_xor(m, off));
            const unsigned long long bl = __ballot(vm == m);
            const int cnt = __popcll(bl);
            if (cnt >= krem) { th = m; break; }
            krem -= cnt; prev = m;
        }
        if (l == 0) thS[r] = th;
    }
    __syncthreads();

    if (w < NH) {
        const int h = w, i = l;
        const float adv = adS[j * NH + h];
        const float a = (i < NC) ? adjS[i * NC + j] : 0.f;
        const bool msk = (i < NC) && ((i == j) || ((a >= thS[i]) && (a != 0.f)));
        float e = 0.f;
        if (msk) { e = asS[i * 5 + h] + adv; e = e > 0.f ? e : 0.2f * e; }
        float m = msk ? e : -INFINITY;
#pragma unroll
        for (int off = 32; off >= 1; off >>= 1) m = fmaxf(m, __shfl_xor(m, off));
        const float p = msk ? __expf(e - m) : 0.f;
        float s = p;
#pragma unroll
        for (int off = 32; off >= 1; off >>= 1) s += __shfl_xor(s, off);
        wS[(h << 6) + l] = p / s;        // 0 for i=63 / unmasked
    }
    __syncthreads();

    const int q = t >> 8, col = t & 255;
    float acc = 0.f;
    const float* hpc = hp + col;
#pragma unroll 8
    for (int e = q * 128; e < q * 128 + 128; ++e)
        acc += wS[e] * hpc[(size_t)e * 256];
    psum[q][col] = acc;
    __syncthreads();
    if (t < ND) out[(size_t)j * ND + t] = psum[0][t] + psum[1][t] + biasc[t];
}

// ============================================================================
extern "C" void kernel_launch(void* const* d_in, const int* in_sizes, int n_in,
                              void* d_out, int out_size, void* d_ws, size_t ws_size,
                              hipStream_t stream) {
    const float* x       = (const float*)d_in[0];
    const float* Wg      = (const float*)d_in[1];
    const float* att_src = (const float*)d_in[2];
    const float* att_dst = (const float*)d_in[3];
    const float* bias_g  = (const float*)d_in[4];
    const float* Wp      = (const float*)d_in[5];
    const float* b_proj  = (const float*)d_in[6];
    float* out = (float*)d_out;
    float* ws  = (float*)d_ws;

    __bf16* WcT    = (__bf16*)ws;                 // 65536 bf16  = 32768 f
    __bf16* WchT   = (__bf16*)(ws + 32768);       // 4*65536 bf16 = 131072 f
    float* pWcT    = ws + 32768 + 131072;         // 8*65536 = 524288
    float* pbias   = pWcT + 8 * 65536;            // 2048
    float* biasc   = pbias + 2048;                // 256
    float* partial = biasc + 256;                 // 1024*4096 = 4,194,304
    float* adj     = partial + 1024 * 4096;       // 3969
    float* hp      = adj + NC * NC;               // 256*256 = 65536
    float* gs      = hp + 65536;                  // 1000
    float* gd      = gs + 1000;                   // 1000
    float* as_     = gd + 1000;                   // 252
    float* ad_     = as_ + 252;                   // 252  (total ~19.7 MB)

    k_gswc<<<1258, 256, 0, stream>>>(Wg, att_src, att_dst, bias_g, Wp,
                                     pWcT, pbias, gs, gd);
    k_wct<<<257, 256, 0, stream>>>(pWcT, pbias, b_proj, WcT, WchT, biasc);
    k_fused<<<1024, 256, 0, stream>>>(x, WcT, biasc, out, partial);
    k_adjred_asad_hp<<<68, 512, 0, stream>>>(partial, x, gs, gd, WchT,
                                             adj, as_, ad_, hp);
    k_out0<<<63, 512, 0, stream>>>(adj, as_, ad_, hp, biasc, out);
}